// Round 1
// baseline (2190.253 us; speedup 1.0000x reference)
//
#include <hip/hip_runtime.h>
#include <hip/hip_bf16.h>
#include <math.h>

#define H 128

// ---------------------------------------------------------------- B-splines
// grid[m] = (m-3)*0.4 - 1.0, m = 0..11  (G=5, K=3 -> 8 basis functions)
__device__ __forceinline__ float gridv(int m) { return (float)(m - 3) * 0.4f - 1.0f; }

__device__ __forceinline__ void bspline8(float x, float* b) {
  float t[11];
#pragma unroll
  for (int m = 0; m < 11; ++m)
    t[m] = (x >= gridv(m) && x < gridv(m + 1)) ? 1.0f : 0.0f;
#pragma unroll
  for (int j = 1; j <= 3; ++j) {
#pragma unroll
    for (int m = 0; m + j < 11; ++m) {
      float den1 = gridv(m + j) - gridv(m);
      float den2 = gridv(m + j + 1) - gridv(m + 1);
      t[m] = (x - gridv(m)) * (1.0f / den1) * t[m] +
             (gridv(m + j + 1) - x) * (1.0f / den2) * t[m + 1];
    }
  }
#pragma unroll
  for (int m = 0; m < 8; ++m) b[m] = t[m];
}

// ---------------------------------------------------------------- GEMM N=128
// out[M][128] = act( alpha * (sum_seg A_seg @ W_seg^T + bias0 (+bias1)) )
// ACT: 1 = tanh(x + b),  2 = lrelu(0.5*(x + b0 + b1))
template <int NSEG, int ACT>
__global__ __launch_bounds__(256) void gemm_n128(
    int M, int segK,
    const float* __restrict__ A0, const float* __restrict__ A1, const float* __restrict__ A2,
    const float* __restrict__ W0, const float* __restrict__ W1, const float* __restrict__ W2,
    const float* __restrict__ bias0, const float* __restrict__ bias1,
    float* __restrict__ out) {
  __shared__ float As[16][68];   // k-major: [k][row], 64 rows + pad
  __shared__ float Bs[16][132];  // k-major: [k][col], 128 cols + pad
  const int tid = threadIdx.x;
  const int rowBase = blockIdx.x * 64;
  const int rb = (tid >> 5) << 3;  // 8-row tile base
  const int cb = (tid & 31) << 2;  // 4-col tile base
  float acc[8][4] = {};

  const int ar = tid >> 2;        // A load: row 0..63
  const int ac = (tid & 3) << 2;  // A load: k 0,4,8,12
  const int bo = tid >> 1;        // B load: out-col 0..127
  const int bk = (tid & 1) << 3;  // B load: k 0 or 8

  const int chunksPerSeg = segK >> 4;
  const int nChunks = NSEG * chunksPerSeg;
  for (int kc = 0; kc < nChunks; ++kc) {
    int seg = kc / chunksPerSeg;
    int koff = (kc - seg * chunksPerSeg) << 4;
    const float* Ap = (NSEG == 1 || seg == 0) ? A0 : ((NSEG > 1 && seg == 1) ? A1 : A2);
    const float* Wp = (NSEG == 1 || seg == 0) ? W0 : ((NSEG > 1 && seg == 1) ? W1 : W2);

    int grow = rowBase + ar;
    float4 av = make_float4(0.f, 0.f, 0.f, 0.f);
    if (grow < M) av = *(const float4*)(Ap + (size_t)grow * segK + koff + ac);
    float4 bv0 = *(const float4*)(Wp + (size_t)bo * segK + koff + bk);
    float4 bv1 = *(const float4*)(Wp + (size_t)bo * segK + koff + bk + 4);

    __syncthreads();
    As[ac + 0][ar] = av.x; As[ac + 1][ar] = av.y; As[ac + 2][ar] = av.z; As[ac + 3][ar] = av.w;
    Bs[bk + 0][bo] = bv0.x; Bs[bk + 1][bo] = bv0.y; Bs[bk + 2][bo] = bv0.z; Bs[bk + 3][bo] = bv0.w;
    Bs[bk + 4][bo] = bv1.x; Bs[bk + 5][bo] = bv1.y; Bs[bk + 6][bo] = bv1.z; Bs[bk + 7][bo] = bv1.w;
    __syncthreads();

#pragma unroll
    for (int k = 0; k < 16; ++k) {
      float4 a0 = *(const float4*)&As[k][rb];
      float4 a1 = *(const float4*)&As[k][rb + 4];
      float4 b = *(const float4*)&Bs[k][cb];
      float a[8] = {a0.x, a0.y, a0.z, a0.w, a1.x, a1.y, a1.z, a1.w};
      float bb[4] = {b.x, b.y, b.z, b.w};
#pragma unroll
      for (int r = 0; r < 8; ++r)
#pragma unroll
        for (int c = 0; c < 4; ++c) acc[r][c] += a[r] * bb[c];
    }
  }

#pragma unroll
  for (int r = 0; r < 8; ++r) {
    int grow = rowBase + rb + r;
    if (grow < M) {
      float v[4];
#pragma unroll
      for (int c = 0; c < 4; ++c) {
        int col = cb + c;
        float x = acc[r][c] + bias0[col];
        if (bias1) x += bias1[col];
        if (ACT == 1) {
          x = tanhf(x);
        } else {
          x *= 0.5f;
          x = (x >= 0.f) ? x : 0.2f * x;
        }
        v[c] = x;
      }
      *(float4*)(out + (size_t)grow * H + cb) = *(float4*)v;
    }
  }
}

// ---------------------------------------------------------------- KAN layer (D inputs -> 128 outs, tanh)
template <int D>
__global__ __launch_bounds__(256) void kan_layer(
    const float* __restrict__ x, const float* __restrict__ base_w,
    const float* __restrict__ spline_w, float* __restrict__ out, int N) {
  constexpr int F = 9 * D;          // silu(D) + bases(D*8)
  __shared__ float wT[F][128];      // wT[j][o]
  __shared__ float fT[F][32];       // fT[j][node]
  const int tid = threadIdx.x;
  for (int idx = tid; idx < F * 128; idx += 256) {
    int j = idx >> 7, o = idx & 127;
    wT[j][o] = (j < D) ? base_w[o * D + j] : spline_w[o * D * 8 + (j - D)];
  }
  const int ng = blockIdx.x * 32;
  for (int idx = tid; idx < 32 * D; idx += 256) {
    int nl = idx / D, i = idx - nl * D;
    int n = ng + nl;
    float xv = (n < N) ? x[(size_t)n * D + i] : 0.f;
    float sg = 1.f / (1.f + expf(-xv));
    float b[8];
    bspline8(xv, b);
    fT[i][nl] = xv * sg;
#pragma unroll
    for (int m = 0; m < 8; ++m) fT[D + i * 8 + m][nl] = b[m];
  }
  __syncthreads();
  const int nb = (tid >> 5) << 2;  // node base 0..28
  const int cb = (tid & 31) << 2;  // col base 0..124
  float acc[4][4] = {};
#pragma unroll
  for (int j = 0; j < F; ++j) {
    float4 f = *(const float4*)&fT[j][nb];
    float4 w = *(const float4*)&wT[j][cb];
    float fa[4] = {f.x, f.y, f.z, f.w}, wa[4] = {w.x, w.y, w.z, w.w};
#pragma unroll
    for (int r = 0; r < 4; ++r)
#pragma unroll
      for (int c = 0; c < 4; ++c) acc[r][c] += fa[r] * wa[c];
  }
#pragma unroll
  for (int r = 0; r < 4; ++r) {
    int n = ng + nb + r;
    if (n < N) {
      float v[4] = {tanhf(acc[r][0]), tanhf(acc[r][1]), tanhf(acc[r][2]), tanhf(acc[r][3])};
      *(float4*)(out + (size_t)n * H + cb) = *(float4*)v;
    }
  }
}

// ---------------------------------------------------------------- CSR build
__global__ void count_kernel(const int* __restrict__ dst, int E, int* __restrict__ cnt) {
  int i = blockIdx.x * blockDim.x + threadIdx.x;
  if (i < E) atomicAdd(&cnt[dst[i]], 1);
}

__global__ void scan_kernel(const int* __restrict__ cnt, int n,
                            int* __restrict__ offs, int* __restrict__ cursor) {
  __shared__ int buf[1024];
  __shared__ int carry;
  int tid = threadIdx.x;
  if (tid == 0) carry = 0;
  __syncthreads();
  for (int base = 0; base < n; base += 1024) {
    int i = base + tid;
    int v = (i < n) ? cnt[i] : 0;
    buf[tid] = v;
    __syncthreads();
    for (int off = 1; off < 1024; off <<= 1) {
      int tv = (tid >= off) ? buf[tid - off] : 0;
      __syncthreads();
      buf[tid] += tv;
      __syncthreads();
    }
    int excl = carry + buf[tid] - v;
    if (i < n) { offs[i] = excl; cursor[i] = excl; }
    __syncthreads();
    if (tid == 0) carry += buf[1023];
    __syncthreads();
  }
  if (tid == 0) offs[n] = carry;
}

__global__ void scatter_kernel(const int* __restrict__ src, const int* __restrict__ dst, int E,
                               int* __restrict__ cursor, int* __restrict__ sorted_src) {
  int i = blockIdx.x * blockDim.x + threadIdx.x;
  if (i < E) {
    int p = atomicAdd(&cursor[dst[i]], 1);
    sorted_src[p] = src[i];
  }
}

// mean aggregation: one block (128 thr) per destination node
__global__ void aggregate_mean(const float* __restrict__ feat, const int* __restrict__ offs,
                               const int* __restrict__ sorted_src, float* __restrict__ agg,
                               int n_dst) {
  int d = blockIdx.x;
  if (d >= n_dst) return;
  int t = threadIdx.x;
  int s0 = offs[d], s1 = offs[d + 1];
  float acc = 0.f;
  for (int k = s0; k < s1; ++k) {
    int src = sorted_src[k];
    acc += feat[(size_t)src * H + t];
  }
  float cnt = (float)(s1 - s0);
  agg[(size_t)d * H + t] = acc / fmaxf(cnt, 1.f);
}

__global__ void add_mat(const float* __restrict__ a, const float* __restrict__ b,
                        float* __restrict__ c, int n) {
  int i = blockIdx.x * blockDim.x + threadIdx.x;
  if (i < n) c[i] = a[i] + b[i];
}

// ---------------------------------------------------------------- BatchNorm stats (combined = [eh | e])
__global__ void bn_stats(const float* __restrict__ eh, const float* __restrict__ e, int M,
                         double* __restrict__ sums) {
  int t = threadIdx.x;  // 256 = channel
  double s = 0.0, s2 = 0.0;
  for (int r = blockIdx.x; r < M; r += gridDim.x) {
    float v = (t < 128) ? eh[(size_t)r * 128 + t] : e[(size_t)r * 128 + (t - 128)];
    s += v;
    s2 += (double)v * v;
  }
  atomicAdd(&sums[t], s);
  atomicAdd(&sums[256 + t], s2);
}

__global__ void bn_finalize(const double* __restrict__ sums, int M,
                            const float* __restrict__ gamma, const float* __restrict__ beta,
                            float* __restrict__ scale, float* __restrict__ shift) {
  int c = threadIdx.x;
  if (c < 256) {
    double mu = sums[c] / M;
    double var = sums[256 + c] / M - mu * mu;
    float rstd = 1.0f / sqrtf((float)var + 1e-5f);
    float g = gamma[c] * rstd;
    scale[c] = g;
    shift[c] = beta[c] - (float)mu * g;
  }
}

// ---------------------------------------------------------------- classifier KAN (256 -> 2), BN fused
__global__ __launch_bounds__(256) void classifier_kan(
    const float* __restrict__ eh, const float* __restrict__ e,
    const float* __restrict__ scale, const float* __restrict__ shift,
    const float* __restrict__ base_w, const float* __restrict__ spline_w,
    float* __restrict__ out, int M) {
  __shared__ float wT[18][256];  // [2 base + 16 spline][channel]
  __shared__ float sc[256], sh[256];
  int tid = threadIdx.x;
  for (int idx = tid; idx < 18 * 256; idx += 256) {
    int k = idx >> 8, c = idx & 255;
    float v;
    if (k < 2) v = base_w[k * 256 + c];
    else {
      int kk = k - 2, o = kk >> 3, b = kk & 7;
      v = spline_w[((size_t)o * 256 + c) * 8 + b];
    }
    wT[k][c] = v;
  }
  sc[tid] = scale[tid];
  sh[tid] = shift[tid];
  __syncthreads();
  int wave = tid >> 6, lane = tid & 63;
  int r = blockIdx.x * 4 + wave;
  if (r >= M) return;
  float a0 = 0.f, a1 = 0.f;
#pragma unroll
  for (int m = 0; m < 4; ++m) {
    int c = lane + (m << 6);
    float xv = (c < 128) ? eh[(size_t)r * 128 + c] : e[(size_t)r * 128 + (c - 128)];
    float y = xv * sc[c] + sh[c];
    float sg = 1.f / (1.f + expf(-y));
    float si = y * sg;
    float b[8];
    bspline8(y, b);
    a0 += si * wT[0][c];
    a1 += si * wT[1][c];
#pragma unroll
    for (int bb = 0; bb < 8; ++bb) {
      a0 += b[bb] * wT[2 + bb][c];
      a1 += b[bb] * wT[10 + bb][c];
    }
  }
#pragma unroll
  for (int off = 32; off >= 1; off >>= 1) {
    a0 += __shfl_down(a0, off);
    a1 += __shfl_down(a1, off);
  }
  if (lane == 0) {
    out[(size_t)r * 2] = a0;
    out[(size_t)r * 2 + 1] = a1;
  }
}

// ---------------------------------------------------------------- launch
extern "C" void kernel_launch(void* const* d_in, const int* in_sizes, int n_in,
                              void* d_out, int out_size, void* d_ws, size_t ws_size,
                              hipStream_t stream) {
  const float* email_x   = (const float*)d_in[0];
  const float* url_x     = (const float*)d_in[1];
  const float* sender_x  = (const float*)d_in[2];
  const float* W_email   = (const float*)d_in[3];
  const float* b_email   = (const float*)d_in[4];
  const float* url_bw    = (const float*)d_in[5];
  const float* url_sw    = (const float*)d_in[6];
  const float* snd_bw    = (const float*)d_in[7];
  const float* snd_sw    = (const float*)d_in[8];
  const float* Wl_se     = (const float*)d_in[9];
  const float* bl_se     = (const float*)d_in[10];
  const float* Wr_se     = (const float*)d_in[11];
  // d_in[12..14]: eu SAGE weights — dead code in the reference (result unused)
  const float* Wl_ue     = (const float*)d_in[15];
  const float* bl_ue     = (const float*)d_in[16];
  const float* Wr_ue     = (const float*)d_in[17];
  const float* bn_gamma  = (const float*)d_in[18];
  const float* bn_beta   = (const float*)d_in[19];
  const float* cls_bw    = (const float*)d_in[20];
  const float* cls_sw    = (const float*)d_in[21];
  const int*   se_src    = (const int*)d_in[22];
  const int*   se_dst    = (const int*)d_in[23];
  // d_in[24..25]: eu edges — dead
  const int*   ue_src    = (const int*)d_in[26];
  const int*   ue_dst    = (const int*)d_in[27];

  const int N_E = in_sizes[0] / 768;
  const int N_U = in_sizes[1] / 8;
  const int N_S = in_sizes[2];
  const int E_SE = in_sizes[22];
  const int E_UE = in_sizes[26];

  char* ws = (char*)d_ws;
  size_t off = 0;
  auto alloc = [&](size_t bytes) -> void* {
    void* p = ws + off;
    off = (off + bytes + 255) & ~(size_t)255;
    return p;
  };

  float* e      = (float*)alloc((size_t)N_E * H * 4);
  float* u      = (float*)alloc((size_t)N_U * H * 4);
  float* s      = (float*)alloc((size_t)N_S * H * 4);
  float* agg_s  = (float*)alloc((size_t)N_E * H * 4);
  float* agg_u  = (float*)alloc((size_t)N_E * H * 4);
  float* Wr_c   = (float*)alloc((size_t)H * H * 4);
  int* cnt_se   = (int*)alloc((size_t)N_E * 4);
  int* offs_se  = (int*)alloc(((size_t)N_E + 1) * 4);
  int* cur_se   = (int*)alloc((size_t)N_E * 4);
  int* srt_se   = (int*)alloc((size_t)E_SE * 4);
  int* cnt_ue   = (int*)alloc((size_t)N_E * 4);
  int* offs_ue  = (int*)alloc(((size_t)N_E + 1) * 4);
  int* cur_ue   = (int*)alloc((size_t)N_E * 4);
  int* srt_ue   = (int*)alloc((size_t)E_UE * 4);
  double* bnsum = (double*)alloc(512 * 8);
  float* scale  = (float*)alloc(256 * 4);
  float* shift  = (float*)alloc(256 * 4);
  // u is dead after aggregate_mean(ue); reuse its space for email_h
  float* eh = u;

  hipMemsetAsync(cnt_se, 0, (size_t)N_E * 4, stream);
  hipMemsetAsync(cnt_ue, 0, (size_t)N_E * 4, stream);
  hipMemsetAsync(bnsum, 0, 512 * 8, stream);

  // node encoders
  gemm_n128<1, 1><<<(N_E + 63) / 64, 256, 0, stream>>>(
      N_E, 768, email_x, nullptr, nullptr, W_email, nullptr, nullptr, b_email, nullptr, e);
  kan_layer<8><<<(N_U + 31) / 32, 256, 0, stream>>>(url_x, url_bw, url_sw, u, N_U);
  kan_layer<1><<<(N_S + 31) / 32, 256, 0, stream>>>(sender_x, snd_bw, snd_sw, s, N_S);

  // CSR build for both email-destination edge sets
  count_kernel<<<(E_SE + 255) / 256, 256, 0, stream>>>(se_dst, E_SE, cnt_se);
  count_kernel<<<(E_UE + 255) / 256, 256, 0, stream>>>(ue_dst, E_UE, cnt_ue);
  scan_kernel<<<1, 1024, 0, stream>>>(cnt_se, N_E, offs_se, cur_se);
  scan_kernel<<<1, 1024, 0, stream>>>(cnt_ue, N_E, offs_ue, cur_ue);
  scatter_kernel<<<(E_SE + 255) / 256, 256, 0, stream>>>(se_src, se_dst, E_SE, cur_se, srt_se);
  scatter_kernel<<<(E_UE + 255) / 256, 256, 0, stream>>>(ue_src, ue_dst, E_UE, cur_ue, srt_ue);

  // mean aggregation (gather, no float atomics)
  aggregate_mean<<<N_E, 128, 0, stream>>>(s, offs_se, srt_se, agg_s, N_E);
  aggregate_mean<<<N_E, 128, 0, stream>>>(u, offs_ue, srt_ue, agg_u, N_E);

  // fused email_h = lrelu(0.5*(agg_s@Wl_se^T + agg_u@Wl_ue^T + e@(Wr_se+Wr_ue)^T + bl_se + bl_ue))
  add_mat<<<(H * H + 255) / 256, 256, 0, stream>>>(Wr_se, Wr_ue, Wr_c, H * H);
  gemm_n128<3, 2><<<(N_E + 63) / 64, 256, 0, stream>>>(
      N_E, 128, agg_s, agg_u, e, Wl_se, Wl_ue, Wr_c, bl_se, bl_ue, eh);

  // batchnorm over combined=[eh|e], then classifier KAN (BN fused into it)
  bn_stats<<<128, 256, 0, stream>>>(eh, e, N_E, bnsum);
  bn_finalize<<<1, 256, 0, stream>>>(bnsum, N_E, bn_gamma, bn_beta, scale, shift);
  classifier_kan<<<(N_E + 3) / 4, 256, 0, stream>>>(
      eh, e, scale, shift, cls_bw, cls_sw, (float*)d_out, N_E);
}

// Round 3
// 890.289 us; speedup vs baseline: 2.4602x; 2.4602x over previous
//
#include <hip/hip_runtime.h>
#include <hip/hip_bf16.h>
#include <math.h>

#define H 128

// ---------------------------------------------------------------- B-splines
// grid[m] = (m-3)*0.4 - 1.0, m = 0..11  (G=5, K=3 -> 8 basis functions)
__device__ __forceinline__ float gridv(int m) { return (float)(m - 3) * 0.4f - 1.0f; }

__device__ __forceinline__ void bspline8(float x, float* b) {
  float t[11];
#pragma unroll
  for (int m = 0; m < 11; ++m)
    t[m] = (x >= gridv(m) && x < gridv(m + 1)) ? 1.0f : 0.0f;
#pragma unroll
  for (int j = 1; j <= 3; ++j) {
#pragma unroll
    for (int m = 0; m + j < 11; ++m) {
      float den1 = gridv(m + j) - gridv(m);
      float den2 = gridv(m + j + 1) - gridv(m + 1);
      t[m] = (x - gridv(m)) * (1.0f / den1) * t[m] +
             (gridv(m + j + 1) - x) * (1.0f / den2) * t[m + 1];
    }
  }
#pragma unroll
  for (int m = 0; m < 8; ++m) b[m] = t[m];
}

// ---------------------------------------------------------------- GEMM N=128
// out[M][128] = act( sum_seg A_seg @ W_seg^T + bias0 (+bias1) )
// ACT: 1 = tanh(x + b),  2 = lrelu(0.5*(x + b0 + b1))
template <int NSEG, int ACT>
__global__ __launch_bounds__(256) void gemm_n128(
    int M, int segK,
    const float* __restrict__ A0, const float* __restrict__ A1, const float* __restrict__ A2,
    const float* __restrict__ W0, const float* __restrict__ W1, const float* __restrict__ W2,
    const float* __restrict__ bias0, const float* __restrict__ bias1,
    float* __restrict__ out) {
  __shared__ float As[16][68];   // k-major: [k][row], 64 rows + pad
  __shared__ float Bs[16][132];  // k-major: [k][col], 128 cols + pad
  const int tid = threadIdx.x;
  const int rowBase = blockIdx.x * 64;
  const int rb = (tid >> 5) << 3;  // 8-row tile base
  const int cb = (tid & 31) << 2;  // 4-col tile base
  float acc[8][4] = {};

  const int ar = tid >> 2;        // A load: row 0..63
  const int ac = (tid & 3) << 2;  // A load: k 0,4,8,12
  const int bo = tid >> 1;        // B load: out-col 0..127
  const int bk = (tid & 1) << 3;  // B load: k 0 or 8

  const int chunksPerSeg = segK >> 4;
  const int nChunks = NSEG * chunksPerSeg;
  for (int kc = 0; kc < nChunks; ++kc) {
    int seg = kc / chunksPerSeg;
    int koff = (kc - seg * chunksPerSeg) << 4;
    const float* Ap = (NSEG == 1 || seg == 0) ? A0 : ((NSEG > 1 && seg == 1) ? A1 : A2);
    const float* Wp = (NSEG == 1 || seg == 0) ? W0 : ((NSEG > 1 && seg == 1) ? W1 : W2);

    int grow = rowBase + ar;
    float4 av = make_float4(0.f, 0.f, 0.f, 0.f);
    if (grow < M) av = *(const float4*)(Ap + (size_t)grow * segK + koff + ac);
    float4 bv0 = *(const float4*)(Wp + (size_t)bo * segK + koff + bk);
    float4 bv1 = *(const float4*)(Wp + (size_t)bo * segK + koff + bk + 4);

    __syncthreads();
    As[ac + 0][ar] = av.x; As[ac + 1][ar] = av.y; As[ac + 2][ar] = av.z; As[ac + 3][ar] = av.w;
    Bs[bk + 0][bo] = bv0.x; Bs[bk + 1][bo] = bv0.y; Bs[bk + 2][bo] = bv0.z; Bs[bk + 3][bo] = bv0.w;
    Bs[bk + 4][bo] = bv1.x; Bs[bk + 5][bo] = bv1.y; Bs[bk + 6][bo] = bv1.z; Bs[bk + 7][bo] = bv1.w;
    __syncthreads();

#pragma unroll
    for (int k = 0; k < 16; ++k) {
      float4 a0 = *(const float4*)&As[k][rb];
      float4 a1 = *(const float4*)&As[k][rb + 4];
      float4 b = *(const float4*)&Bs[k][cb];
      float a[8] = {a0.x, a0.y, a0.z, a0.w, a1.x, a1.y, a1.z, a1.w};
      float bb[4] = {b.x, b.y, b.z, b.w};
#pragma unroll
      for (int r = 0; r < 8; ++r)
#pragma unroll
        for (int c = 0; c < 4; ++c) acc[r][c] += a[r] * bb[c];
    }
  }

#pragma unroll
  for (int r = 0; r < 8; ++r) {
    int grow = rowBase + rb + r;
    if (grow < M) {
      float v[4];
#pragma unroll
      for (int c = 0; c < 4; ++c) {
        int col = cb + c;
        float x = acc[r][c] + bias0[col];
        if (bias1) x += bias1[col];
        if (ACT == 1) {
          x = tanhf(x);
        } else {
          x *= 0.5f;
          x = (x >= 0.f) ? x : 0.2f * x;
        }
        v[c] = x;
      }
      *(float4*)(out + (size_t)grow * H + cb) = *(float4*)v;
    }
  }
}

// ---------------------------------------------------------------- pack KAN weights into padded [128][KP]
// Wpad[o][k] = k<D ? base_w[o*D+k] : (k<9D ? spline_w[o*D*8 + (k-D)] : 0)
__global__ void build_wpad(const float* __restrict__ base_w, const float* __restrict__ spline_w,
                           float* __restrict__ Wpad, int D, int KP) {
  int idx = blockIdx.x * blockDim.x + threadIdx.x;
  if (idx >= 128 * KP) return;
  int o = idx / KP, k = idx - o * KP;
  float v = 0.f;
  if (k < D) v = base_w[o * D + k];
  else if (k < 9 * D) v = spline_w[o * D * 8 + (k - D)];
  Wpad[idx] = v;
}

// ---------------------------------------------------------------- fused KAN as GEMM (D inputs -> 128, tanh)
// Features computed once per 64-node tile into persistent k-major LDS A-tile,
// then the proven gemm_n128 FMA structure over KP (padded 9*D) with Wpad.
template <int D>
__global__ __launch_bounds__(256) void kan_gemm(
    const float* __restrict__ x, const float* __restrict__ Wpad,
    float* __restrict__ out, int N) {
  constexpr int KP = (9 * D + 15) & ~15;  // D=8 -> 80, D=1 -> 16
  __shared__ float As[KP][68];   // k-major persistent feature tile
  __shared__ float Bs[16][132];
  const int tid = threadIdx.x;
  const int rowBase = blockIdx.x * 64;

  // feature fill: one (node, input) pair per item
  for (int idx = tid; idx < 64 * D; idx += 256) {
    int nl = idx / D, i = idx - nl * D;
    int n = rowBase + nl;
    float xv = (n < N) ? x[(size_t)n * D + i] : 0.f;
    float sg = 1.f / (1.f + expf(-xv));
    float b[8];
    bspline8(xv, b);
    As[i][nl] = xv * sg;
#pragma unroll
    for (int m = 0; m < 8; ++m) As[D + i * 8 + m][nl] = b[m];
  }
  // zero the pad rows (k = 9D .. KP-1)
  for (int idx = tid; idx < (KP - 9 * D) * 64; idx += 256) {
    int r = idx >> 6, c = idx & 63;
    As[9 * D + r][c] = 0.f;
  }

  const int rb = (tid >> 5) << 3;
  const int cb = (tid & 31) << 2;
  const int bo = tid >> 1;
  const int bk = (tid & 1) << 3;
  float acc[8][4] = {};

  for (int kc = 0; kc < KP / 16; ++kc) {
    int koff = kc << 4;
    float4 bv0 = *(const float4*)(Wpad + (size_t)bo * KP + koff + bk);
    float4 bv1 = *(const float4*)(Wpad + (size_t)bo * KP + koff + bk + 4);
    __syncthreads();  // (kc==0: also covers feature fill)
    Bs[bk + 0][bo] = bv0.x; Bs[bk + 1][bo] = bv0.y; Bs[bk + 2][bo] = bv0.z; Bs[bk + 3][bo] = bv0.w;
    Bs[bk + 4][bo] = bv1.x; Bs[bk + 5][bo] = bv1.y; Bs[bk + 6][bo] = bv1.z; Bs[bk + 7][bo] = bv1.w;
    __syncthreads();
#pragma unroll
    for (int k = 0; k < 16; ++k) {
      float4 a0 = *(const float4*)&As[koff + k][rb];
      float4 a1 = *(const float4*)&As[koff + k][rb + 4];
      float4 b = *(const float4*)&Bs[k][cb];
      float a[8] = {a0.x, a0.y, a0.z, a0.w, a1.x, a1.y, a1.z, a1.w};
      float bb[4] = {b.x, b.y, b.z, b.w};
#pragma unroll
      for (int r = 0; r < 8; ++r)
#pragma unroll
        for (int c = 0; c < 4; ++c) acc[r][c] += a[r] * bb[c];
    }
  }

#pragma unroll
  for (int r = 0; r < 8; ++r) {
    int n = rowBase + rb + r;
    if (n < N) {
      float v[4] = {tanhf(acc[r][0]), tanhf(acc[r][1]), tanhf(acc[r][2]), tanhf(acc[r][3])};
      *(float4*)(out + (size_t)n * H + cb) = *(float4*)v;
    }
  }
}

// ---------------------------------------------------------------- CSR build
__global__ void count_kernel(const int* __restrict__ dst, int E, int* __restrict__ cnt) {
  int i = blockIdx.x * blockDim.x + threadIdx.x;
  if (i < E) atomicAdd(&cnt[dst[i]], 1);
}

__global__ void scan_kernel(const int* __restrict__ cnt, int n,
                            int* __restrict__ offs, int* __restrict__ cursor) {
  __shared__ int buf[1024];
  __shared__ int carry;
  int tid = threadIdx.x;
  if (tid == 0) carry = 0;
  __syncthreads();
  for (int base = 0; base < n; base += 1024) {
    int i = base + tid;
    int v = (i < n) ? cnt[i] : 0;
    buf[tid] = v;
    __syncthreads();
    for (int off = 1; off < 1024; off <<= 1) {
      int tv = (tid >= off) ? buf[tid - off] : 0;
      __syncthreads();
      buf[tid] += tv;
      __syncthreads();
    }
    int excl = carry + buf[tid] - v;
    if (i < n) { offs[i] = excl; cursor[i] = excl; }
    __syncthreads();
    if (tid == 0) carry += buf[1023];
    __syncthreads();
  }
  if (tid == 0) offs[n] = carry;
}

__global__ void scatter_kernel(const int* __restrict__ src, const int* __restrict__ dst, int E,
                               int* __restrict__ cursor, int* __restrict__ sorted_src) {
  int i = blockIdx.x * blockDim.x + threadIdx.x;
  if (i < E) {
    int p = atomicAdd(&cursor[dst[i]], 1);
    sorted_src[p] = src[i];
  }
}

// mean aggregation: one wave (64 lanes, float2 each) per destination node, 4 dst/block
__global__ __launch_bounds__(256) void aggregate_mean(
    const float* __restrict__ feat, const int* __restrict__ offs,
    const int* __restrict__ sorted_src, float* __restrict__ agg, int n_dst) {
  int d = (blockIdx.x << 2) + (threadIdx.x >> 6);
  if (d >= n_dst) return;
  int lane = threadIdx.x & 63;
  int s0 = offs[d], s1 = offs[d + 1];
  float ax = 0.f, ay = 0.f;
  const float* base = feat + (lane << 1);
  for (int k = s0; k < s1; ++k) {
    int src = sorted_src[k];
    float2 v = *(const float2*)(base + (size_t)src * H);
    ax += v.x;
    ay += v.y;
  }
  float inv = 1.f / fmaxf((float)(s1 - s0), 1.f);
  *(float2*)(agg + (size_t)d * H + (lane << 1)) = make_float2(ax * inv, ay * inv);
}

__global__ void add_mat(const float* __restrict__ a, const float* __restrict__ b,
                        float* __restrict__ c, int n) {
  int i = blockIdx.x * blockDim.x + threadIdx.x;
  if (i < n) c[i] = a[i] + b[i];
}

// ---------------------------------------------------------------- BatchNorm stats (combined = [eh | e])
__global__ void bn_stats(const float* __restrict__ eh, const float* __restrict__ e, int M,
                         double* __restrict__ sums) {
  int t = threadIdx.x;  // 256 = channel
  double s = 0.0, s2 = 0.0;
  for (int r = blockIdx.x; r < M; r += gridDim.x) {
    float v = (t < 128) ? eh[(size_t)r * 128 + t] : e[(size_t)r * 128 + (t - 128)];
    s += v;
    s2 += (double)v * v;
  }
  atomicAdd(&sums[t], s);
  atomicAdd(&sums[256 + t], s2);
}

__global__ void bn_finalize(const double* __restrict__ sums, int M,
                            const float* __restrict__ gamma, const float* __restrict__ beta,
                            float* __restrict__ scale, float* __restrict__ shift) {
  int c = threadIdx.x;
  if (c < 256) {
    double mu = sums[c] / M;
    double var = sums[256 + c] / M - mu * mu;
    float rstd = 1.0f / sqrtf((float)var + 1e-5f);
    float g = gamma[c] * rstd;
    scale[c] = g;
    shift[c] = beta[c] - (float)mu * g;
  }
}

// ---------------------------------------------------------------- classifier KAN (256 -> 2), BN fused
__global__ __launch_bounds__(256) void classifier_kan(
    const float* __restrict__ eh, const float* __restrict__ e,
    const float* __restrict__ scale, const float* __restrict__ shift,
    const float* __restrict__ base_w, const float* __restrict__ spline_w,
    float* __restrict__ out, int M) {
  __shared__ float wT[18][256];  // [2 base + 16 spline][channel]
  __shared__ float sc[256], sh[256];
  int tid = threadIdx.x;
  for (int idx = tid; idx < 18 * 256; idx += 256) {
    int k = idx >> 8, c = idx & 255;
    float v;
    if (k < 2) v = base_w[k * 256 + c];
    else {
      int kk = k - 2, o = kk >> 3, b = kk & 7;
      v = spline_w[((size_t)o * 256 + c) * 8 + b];
    }
    wT[k][c] = v;
  }
  sc[tid] = scale[tid];
  sh[tid] = shift[tid];
  __syncthreads();
  int wave = tid >> 6, lane = tid & 63;
  int r = blockIdx.x * 4 + wave;
  if (r >= M) return;
  float a0 = 0.f, a1 = 0.f;
#pragma unroll
  for (int m = 0; m < 4; ++m) {
    int c = lane + (m << 6);
    float xv = (c < 128) ? eh[(size_t)r * 128 + c] : e[(size_t)r * 128 + (c - 128)];
    float y = xv * sc[c] + sh[c];
    float sg = 1.f / (1.f + expf(-y));
    float si = y * sg;
    float b[8];
    bspline8(y, b);
    a0 += si * wT[0][c];
    a1 += si * wT[1][c];
#pragma unroll
    for (int bb = 0; bb < 8; ++bb) {
      a0 += b[bb] * wT[2 + bb][c];
      a1 += b[bb] * wT[10 + bb][c];
    }
  }
#pragma unroll
  for (int off = 32; off >= 1; off >>= 1) {
    a0 += __shfl_down(a0, off);
    a1 += __shfl_down(a1, off);
  }
  if (lane == 0) {
    out[(size_t)r * 2] = a0;
    out[(size_t)r * 2 + 1] = a1;
  }
}

// ---------------------------------------------------------------- launch
extern "C" void kernel_launch(void* const* d_in, const int* in_sizes, int n_in,
                              void* d_out, int out_size, void* d_ws, size_t ws_size,
                              hipStream_t stream) {
  const float* email_x   = (const float*)d_in[0];
  const float* url_x     = (const float*)d_in[1];
  const float* sender_x  = (const float*)d_in[2];
  const float* W_email   = (const float*)d_in[3];
  const float* b_email   = (const float*)d_in[4];
  const float* url_bw    = (const float*)d_in[5];
  const float* url_sw    = (const float*)d_in[6];
  const float* snd_bw    = (const float*)d_in[7];
  const float* snd_sw    = (const float*)d_in[8];
  const float* Wl_se     = (const float*)d_in[9];
  const float* bl_se     = (const float*)d_in[10];
  const float* Wr_se     = (const float*)d_in[11];
  // d_in[12..14]: eu SAGE weights — dead code in the reference (result unused)
  const float* Wl_ue     = (const float*)d_in[15];
  const float* bl_ue     = (const float*)d_in[16];
  const float* Wr_ue     = (const float*)d_in[17];
  const float* bn_gamma  = (const float*)d_in[18];
  const float* bn_beta   = (const float*)d_in[19];
  const float* cls_bw    = (const float*)d_in[20];
  const float* cls_sw    = (const float*)d_in[21];
  const int*   se_src    = (const int*)d_in[22];
  const int*   se_dst    = (const int*)d_in[23];
  // d_in[24..25]: eu edges — dead
  const int*   ue_src    = (const int*)d_in[26];
  const int*   ue_dst    = (const int*)d_in[27];

  const int N_E = in_sizes[0] / 768;
  const int N_U = in_sizes[1] / 8;
  const int N_S = in_sizes[2];
  const int E_SE = in_sizes[22];
  const int E_UE = in_sizes[26];

  char* ws = (char*)d_ws;
  size_t off = 0;
  auto alloc = [&](size_t bytes) -> void* {
    void* p = ws + off;
    off = (off + bytes + 255) & ~(size_t)255;
    return p;
  };

  float* e      = (float*)alloc((size_t)N_E * H * 4);
  float* u      = (float*)alloc((size_t)N_U * H * 4);
  float* s      = (float*)alloc((size_t)N_S * H * 4);
  float* agg_s  = (float*)alloc((size_t)N_E * H * 4);
  float* agg_u  = (float*)alloc((size_t)N_E * H * 4);
  float* Wr_c   = (float*)alloc((size_t)H * H * 4);
  float* wpad_u = (float*)alloc((size_t)128 * 80 * 4);
  float* wpad_s = (float*)alloc((size_t)128 * 16 * 4);
  int* cnt_se   = (int*)alloc((size_t)N_E * 4);
  int* offs_se  = (int*)alloc(((size_t)N_E + 1) * 4);
  int* cur_se   = (int*)alloc((size_t)N_E * 4);
  int* srt_se   = (int*)alloc((size_t)E_SE * 4);
  int* cnt_ue   = (int*)alloc((size_t)N_E * 4);
  int* offs_ue  = (int*)alloc(((size_t)N_E + 1) * 4);
  int* cur_ue   = (int*)alloc((size_t)N_E * 4);
  int* srt_ue   = (int*)alloc((size_t)E_UE * 4);
  double* bnsum = (double*)alloc(512 * 8);
  float* scale  = (float*)alloc(256 * 4);
  float* shift  = (float*)alloc(256 * 4);
  // u is dead after aggregate_mean(ue); reuse its space for email_h
  float* eh = u;

  hipMemsetAsync(cnt_se, 0, (size_t)N_E * 4, stream);
  hipMemsetAsync(cnt_ue, 0, (size_t)N_E * 4, stream);
  hipMemsetAsync(bnsum, 0, 512 * 8, stream);

  // pack KAN weights (tiny)
  build_wpad<<<(128 * 80 + 255) / 256, 256, 0, stream>>>(url_bw, url_sw, wpad_u, 8, 80);
  build_wpad<<<(128 * 16 + 255) / 256, 256, 0, stream>>>(snd_bw, snd_sw, wpad_s, 1, 16);

  // node encoders
  gemm_n128<1, 1><<<(N_E + 63) / 64, 256, 0, stream>>>(
      N_E, 768, email_x, nullptr, nullptr, W_email, nullptr, nullptr, b_email, nullptr, e);
  kan_gemm<8><<<(N_U + 63) / 64, 256, 0, stream>>>(url_x, wpad_u, u, N_U);
  kan_gemm<1><<<(N_S + 63) / 64, 256, 0, stream>>>(sender_x, wpad_s, s, N_S);

  // CSR build for both email-destination edge sets
  count_kernel<<<(E_SE + 255) / 256, 256, 0, stream>>>(se_dst, E_SE, cnt_se);
  count_kernel<<<(E_UE + 255) / 256, 256, 0, stream>>>(ue_dst, E_UE, cnt_ue);
  scan_kernel<<<1, 1024, 0, stream>>>(cnt_se, N_E, offs_se, cur_se);
  scan_kernel<<<1, 1024, 0, stream>>>(cnt_ue, N_E, offs_ue, cur_ue);
  scatter_kernel<<<(E_SE + 255) / 256, 256, 0, stream>>>(se_src, se_dst, E_SE, cur_se, srt_se);
  scatter_kernel<<<(E_UE + 255) / 256, 256, 0, stream>>>(ue_src, ue_dst, E_UE, cur_ue, srt_ue);

  // mean aggregation (gather, no float atomics)
  aggregate_mean<<<(N_E + 3) / 4, 256, 0, stream>>>(s, offs_se, srt_se, agg_s, N_E);
  aggregate_mean<<<(N_E + 3) / 4, 256, 0, stream>>>(u, offs_ue, srt_ue, agg_u, N_E);

  // fused email_h = lrelu(0.5*(agg_s@Wl_se^T + agg_u@Wl_ue^T + e@(Wr_se+Wr_ue)^T + bl_se + bl_ue))
  add_mat<<<(H * H + 255) / 256, 256, 0, stream>>>(Wr_se, Wr_ue, Wr_c, H * H);
  gemm_n128<3, 2><<<(N_E + 63) / 64, 256, 0, stream>>>(
      N_E, 128, agg_s, agg_u, e, Wl_se, Wl_ue, Wr_c, bl_se, bl_ue, eh);

  // batchnorm over combined=[eh|e], then classifier KAN (BN fused into it)
  bn_stats<<<128, 256, 0, stream>>>(eh, e, N_E, bnsum);
  bn_finalize<<<1, 256, 0, stream>>>(bnsum, N_E, bn_gamma, bn_beta, scale, shift);
  classifier_kan<<<(N_E + 3) / 4, 256, 0, stream>>>(
      eh, e, scale, shift, cls_bw, cls_sw, (float*)d_out, N_E);
}

// Round 4
// 812.322 us; speedup vs baseline: 2.6963x; 1.0960x over previous
//
#include <hip/hip_runtime.h>
#include <hip/hip_bf16.h>
#include <math.h>

#define H 128

// ---------------------------------------------------------------- B-splines
// grid[m] = (m-3)*0.4 - 1.0, m = 0..11  (G=5, K=3 -> 8 basis functions)
__device__ __forceinline__ float gridv(int m) { return (float)(m - 3) * 0.4f - 1.0f; }

__device__ __forceinline__ void bspline8(float x, float* b) {
  float t[11];
#pragma unroll
  for (int m = 0; m < 11; ++m)
    t[m] = (x >= gridv(m) && x < gridv(m + 1)) ? 1.0f : 0.0f;
#pragma unroll
  for (int j = 1; j <= 3; ++j) {
#pragma unroll
    for (int m = 0; m + j < 11; ++m) {
      float den1 = gridv(m + j) - gridv(m);
      float den2 = gridv(m + j + 1) - gridv(m + 1);
      t[m] = (x - gridv(m)) * (1.0f / den1) * t[m] +
             (gridv(m + j + 1) - x) * (1.0f / den2) * t[m + 1];
    }
  }
#pragma unroll
  for (int m = 0; m < 8; ++m) b[m] = t[m];
}

// ---------------------------------------------------------------- GEMM N=128, 32-row M-tile
// out[M][128] = act( sum_seg A_seg @ W_seg^T + bias0 (+bias1) )
// ACT: 1 = tanh(x + b),  2 = lrelu(0.5*(x + b0 + b1))
// 256 thr: 8 row-groups x 32 col-groups, 4x4 per-thread tile. 938 blocks at
// M=30000 -> ~3.7 waves/SIMD (vs 1.8 with the old 64-row tile that ran at
// VALUBusy 41% / occupancy 18%).
template <int NSEG, int ACT>
__global__ __launch_bounds__(256) void gemm_n128(
    int M, int segK,
    const float* __restrict__ A0, const float* __restrict__ A1, const float* __restrict__ A2,
    const float* __restrict__ W0, const float* __restrict__ W1, const float* __restrict__ W2,
    const float* __restrict__ bias0, const float* __restrict__ bias1,
    float* __restrict__ out) {
  __shared__ float As[16][36];   // k-major: [k][row], 32 rows + pad
  __shared__ float Bs[16][132];  // k-major: [k][col], 128 cols + pad
  const int tid = threadIdx.x;
  const int rowBase = blockIdx.x * 32;
  const int rb = (tid >> 5) << 2;  // 4-row tile base 0..28
  const int cb = (tid & 31) << 2;  // 4-col tile base 0..124
  float acc[4][4] = {};

  const int ar = tid >> 2;        // A load: row 0..63 (only 0..31 active)
  const int ac = (tid & 3) << 2;  // A load: k 0,4,8,12
  const int bo = tid >> 1;        // B load: out-col 0..127
  const int bk = (tid & 1) << 3;  // B load: k 0 or 8

  const int chunksPerSeg = segK >> 4;
  const int nChunks = NSEG * chunksPerSeg;
  for (int kc = 0; kc < nChunks; ++kc) {
    int seg = kc / chunksPerSeg;
    int koff = (kc - seg * chunksPerSeg) << 4;
    const float* Ap = (NSEG == 1 || seg == 0) ? A0 : ((NSEG > 1 && seg == 1) ? A1 : A2);
    const float* Wp = (NSEG == 1 || seg == 0) ? W0 : ((NSEG > 1 && seg == 1) ? W1 : W2);

    float4 av = make_float4(0.f, 0.f, 0.f, 0.f);
    if (ar < 32) {
      int grow = rowBase + ar;
      if (grow < M) av = *(const float4*)(Ap + (size_t)grow * segK + koff + ac);
    }
    float4 bv0 = *(const float4*)(Wp + (size_t)bo * segK + koff + bk);
    float4 bv1 = *(const float4*)(Wp + (size_t)bo * segK + koff + bk + 4);

    __syncthreads();
    if (ar < 32) {
      As[ac + 0][ar] = av.x; As[ac + 1][ar] = av.y; As[ac + 2][ar] = av.z; As[ac + 3][ar] = av.w;
    }
    Bs[bk + 0][bo] = bv0.x; Bs[bk + 1][bo] = bv0.y; Bs[bk + 2][bo] = bv0.z; Bs[bk + 3][bo] = bv0.w;
    Bs[bk + 4][bo] = bv1.x; Bs[bk + 5][bo] = bv1.y; Bs[bk + 6][bo] = bv1.z; Bs[bk + 7][bo] = bv1.w;
    __syncthreads();

#pragma unroll
    for (int k = 0; k < 16; ++k) {
      float4 a = *(const float4*)&As[k][rb];
      float4 b = *(const float4*)&Bs[k][cb];
      float aa[4] = {a.x, a.y, a.z, a.w};
      float bb[4] = {b.x, b.y, b.z, b.w};
#pragma unroll
      for (int r = 0; r < 4; ++r)
#pragma unroll
        for (int c = 0; c < 4; ++c) acc[r][c] += aa[r] * bb[c];
    }
  }

#pragma unroll
  for (int r = 0; r < 4; ++r) {
    int grow = rowBase + rb + r;
    if (grow < M) {
      float v[4];
#pragma unroll
      for (int c = 0; c < 4; ++c) {
        int col = cb + c;
        float x = acc[r][c] + bias0[col];
        if (bias1) x += bias1[col];
        if (ACT == 1) {
          x = tanhf(x);
        } else {
          x *= 0.5f;
          x = (x >= 0.f) ? x : 0.2f * x;
        }
        v[c] = x;
      }
      *(float4*)(out + (size_t)grow * H + cb) = *(float4*)v;
    }
  }
}

// ---------------------------------------------------------------- pack KAN weights into padded [128][KP]
__global__ void build_wpad(const float* __restrict__ base_w, const float* __restrict__ spline_w,
                           float* __restrict__ Wpad, int D, int KP) {
  int idx = blockIdx.x * blockDim.x + threadIdx.x;
  if (idx >= 128 * KP) return;
  int o = idx / KP, k = idx - o * KP;
  float v = 0.f;
  if (k < D) v = base_w[o * D + k];
  else if (k < 9 * D) v = spline_w[o * D * 8 + (k - D)];
  Wpad[idx] = v;
}

// ---------------------------------------------------------------- fused KAN as GEMM (D inputs -> 128, tanh)
template <int D>
__global__ __launch_bounds__(256) void kan_gemm(
    const float* __restrict__ x, const float* __restrict__ Wpad,
    float* __restrict__ out, int N) {
  constexpr int KP = (9 * D + 15) & ~15;  // D=8 -> 80, D=1 -> 16
  __shared__ float As[KP][68];   // k-major persistent feature tile
  __shared__ float Bs[16][132];
  const int tid = threadIdx.x;
  const int rowBase = blockIdx.x * 64;

  // feature fill: one (node, input) pair per item
  for (int idx = tid; idx < 64 * D; idx += 256) {
    int nl = idx / D, i = idx - nl * D;
    int n = rowBase + nl;
    float xv = (n < N) ? x[(size_t)n * D + i] : 0.f;
    float sg = 1.f / (1.f + expf(-xv));
    float b[8];
    bspline8(xv, b);
    As[i][nl] = xv * sg;
#pragma unroll
    for (int m = 0; m < 8; ++m) As[D + i * 8 + m][nl] = b[m];
  }
  // zero the pad rows (k = 9D .. KP-1)
  for (int idx = tid; idx < (KP - 9 * D) * 64; idx += 256) {
    int r = idx >> 6, c = idx & 63;
    As[9 * D + r][c] = 0.f;
  }

  const int rb = (tid >> 5) << 3;
  const int cb = (tid & 31) << 2;
  const int bo = tid >> 1;
  const int bk = (tid & 1) << 3;
  float acc[8][4] = {};

  for (int kc = 0; kc < KP / 16; ++kc) {
    int koff = kc << 4;
    float4 bv0 = *(const float4*)(Wpad + (size_t)bo * KP + koff + bk);
    float4 bv1 = *(const float4*)(Wpad + (size_t)bo * KP + koff + bk + 4);
    __syncthreads();  // (kc==0: also covers feature fill)
    Bs[bk + 0][bo] = bv0.x; Bs[bk + 1][bo] = bv0.y; Bs[bk + 2][bo] = bv0.z; Bs[bk + 3][bo] = bv0.w;
    Bs[bk + 4][bo] = bv1.x; Bs[bk + 5][bo] = bv1.y; Bs[bk + 6][bo] = bv1.z; Bs[bk + 7][bo] = bv1.w;
    __syncthreads();
#pragma unroll
    for (int k = 0; k < 16; ++k) {
      float4 a0 = *(const float4*)&As[koff + k][rb];
      float4 a1 = *(const float4*)&As[koff + k][rb + 4];
      float4 b = *(const float4*)&Bs[k][cb];
      float a[8] = {a0.x, a0.y, a0.z, a0.w, a1.x, a1.y, a1.z, a1.w};
      float bb[4] = {b.x, b.y, b.z, b.w};
#pragma unroll
      for (int r = 0; r < 8; ++r)
#pragma unroll
        for (int c = 0; c < 4; ++c) acc[r][c] += a[r] * bb[c];
    }
  }

#pragma unroll
  for (int r = 0; r < 8; ++r) {
    int n = rowBase + rb + r;
    if (n < N) {
      float v[4] = {tanhf(acc[r][0]), tanhf(acc[r][1]), tanhf(acc[r][2]), tanhf(acc[r][3])};
      *(float4*)(out + (size_t)n * H + cb) = *(float4*)v;
    }
  }
}

// ---------------------------------------------------------------- CSR build
__global__ void count_kernel(const int* __restrict__ dst, int E, int* __restrict__ cnt) {
  int i = blockIdx.x * blockDim.x + threadIdx.x;
  if (i < E) atomicAdd(&cnt[dst[i]], 1);
}

// single-block scan, wave-shuffle based: 3 barriers / 1024-chunk (was 20)
__global__ __launch_bounds__(1024) void scan_kernel(
    const int* __restrict__ cnt, int n, int* __restrict__ offs, int* __restrict__ cursor) {
  __shared__ int wsum[16];
  __shared__ int carry_s;
  const int tid = threadIdx.x;
  const int lane = tid & 63;
  const int wid = tid >> 6;
  if (tid == 0) carry_s = 0;
  __syncthreads();
  for (int base = 0; base < n; base += 1024) {
    int i = base + tid;
    int v = (i < n) ? cnt[i] : 0;
    // inclusive wave scan
    int x = v;
#pragma unroll
    for (int off = 1; off < 64; off <<= 1) {
      int t = __shfl_up(x, off);
      if (lane >= off) x += t;
    }
    if (lane == 63) wsum[wid] = x;
    __syncthreads();
    if (wid == 0) {
      int w = (lane < 16) ? wsum[lane] : 0;
#pragma unroll
      for (int off = 1; off < 16; off <<= 1) {
        int t = __shfl_up(w, off);
        if (lane >= off) w += t;
      }
      if (lane < 16) wsum[lane] = w;
    }
    __syncthreads();
    int waveoff = (wid == 0) ? 0 : wsum[wid - 1];
    int excl = carry_s + waveoff + (x - v);
    if (i < n) { offs[i] = excl; cursor[i] = excl; }
    int total = wsum[15];
    __syncthreads();
    if (tid == 0) carry_s += total;
    __syncthreads();
  }
  if (threadIdx.x == 0) offs[n] = carry_s;
}

__global__ void scatter_kernel(const int* __restrict__ src, const int* __restrict__ dst, int E,
                               int* __restrict__ cursor, int* __restrict__ sorted_src) {
  int i = blockIdx.x * blockDim.x + threadIdx.x;
  if (i < E) {
    int p = atomicAdd(&cursor[dst[i]], 1);
    sorted_src[p] = src[i];
  }
}

// mean aggregation: one wave (64 lanes, float2 each) per destination node,
// 4 dst/block, 2 edge-rows in flight for memory-level parallelism
__global__ __launch_bounds__(256) void aggregate_mean(
    const float* __restrict__ feat, const int* __restrict__ offs,
    const int* __restrict__ sorted_src, float* __restrict__ agg, int n_dst) {
  int d = (blockIdx.x << 2) + (threadIdx.x >> 6);
  if (d >= n_dst) return;
  int lane = threadIdx.x & 63;
  int s0 = offs[d], s1 = offs[d + 1];
  float ax = 0.f, ay = 0.f;
  const float* base = feat + (lane << 1);
  int k = s0;
  for (; k + 1 < s1; k += 2) {
    int i0 = sorted_src[k];
    int i1 = sorted_src[k + 1];
    float2 v0 = *(const float2*)(base + (size_t)i0 * H);
    float2 v1 = *(const float2*)(base + (size_t)i1 * H);
    ax += v0.x + v1.x;
    ay += v0.y + v1.y;
  }
  if (k < s1) {
    int i0 = sorted_src[k];
    float2 v0 = *(const float2*)(base + (size_t)i0 * H);
    ax += v0.x;
    ay += v0.y;
  }
  float inv = 1.f / fmaxf((float)(s1 - s0), 1.f);
  *(float2*)(agg + (size_t)d * H + (lane << 1)) = make_float2(ax * inv, ay * inv);
}

__global__ void add_mat(const float* __restrict__ a, const float* __restrict__ b,
                        float* __restrict__ c, int n) {
  int i = blockIdx.x * blockDim.x + threadIdx.x;
  if (i < n) c[i] = a[i] + b[i];
}

// ---------------------------------------------------------------- BatchNorm stats (combined = [eh | e])
__global__ void bn_stats(const float* __restrict__ eh, const float* __restrict__ e, int M,
                         double* __restrict__ sums) {
  int t = threadIdx.x;  // 256 = channel
  double s = 0.0, s2 = 0.0;
  for (int r = blockIdx.x; r < M; r += gridDim.x) {
    float v = (t < 128) ? eh[(size_t)r * 128 + t] : e[(size_t)r * 128 + (t - 128)];
    s += v;
    s2 += (double)v * v;
  }
  atomicAdd(&sums[t], s);
  atomicAdd(&sums[256 + t], s2);
}

__global__ void bn_finalize(const double* __restrict__ sums, int M,
                            const float* __restrict__ gamma, const float* __restrict__ beta,
                            float* __restrict__ scale, float* __restrict__ shift) {
  int c = threadIdx.x;
  if (c < 256) {
    double mu = sums[c] / M;
    double var = sums[256 + c] / M - mu * mu;
    float rstd = 1.0f / sqrtf((float)var + 1e-5f);
    float g = gamma[c] * rstd;
    scale[c] = g;
    shift[c] = beta[c] - (float)mu * g;
  }
}

// ---------------------------------------------------------------- classifier KAN (256 -> 2), BN fused
__global__ __launch_bounds__(256) void classifier_kan(
    const float* __restrict__ eh, const float* __restrict__ e,
    const float* __restrict__ scale, const float* __restrict__ shift,
    const float* __restrict__ base_w, const float* __restrict__ spline_w,
    float* __restrict__ out, int M) {
  __shared__ float wT[18][256];  // [2 base + 16 spline][channel]
  __shared__ float sc[256], sh[256];
  int tid = threadIdx.x;
  for (int idx = tid; idx < 18 * 256; idx += 256) {
    int k = idx >> 8, c = idx & 255;
    float v;
    if (k < 2) v = base_w[k * 256 + c];
    else {
      int kk = k - 2, o = kk >> 3, b = kk & 7;
      v = spline_w[((size_t)o * 256 + c) * 8 + b];
    }
    wT[k][c] = v;
  }
  sc[tid] = scale[tid];
  sh[tid] = shift[tid];
  __syncthreads();
  int wave = tid >> 6, lane = tid & 63;
  int r = blockIdx.x * 4 + wave;
  if (r >= M) return;
  float a0 = 0.f, a1 = 0.f;
#pragma unroll
  for (int m = 0; m < 4; ++m) {
    int c = lane + (m << 6);
    float xv = (c < 128) ? eh[(size_t)r * 128 + c] : e[(size_t)r * 128 + (c - 128)];
    float y = xv * sc[c] + sh[c];
    float sg = 1.f / (1.f + expf(-y));
    float si = y * sg;
    float b[8];
    bspline8(y, b);
    a0 += si * wT[0][c];
    a1 += si * wT[1][c];
#pragma unroll
    for (int bb = 0; bb < 8; ++bb) {
      a0 += b[bb] * wT[2 + bb][c];
      a1 += b[bb] * wT[10 + bb][c];
    }
  }
#pragma unroll
  for (int off = 32; off >= 1; off >>= 1) {
    a0 += __shfl_down(a0, off);
    a1 += __shfl_down(a1, off);
  }
  if (lane == 0) {
    out[(size_t)r * 2] = a0;
    out[(size_t)r * 2 + 1] = a1;
  }
}

// ---------------------------------------------------------------- launch
extern "C" void kernel_launch(void* const* d_in, const int* in_sizes, int n_in,
                              void* d_out, int out_size, void* d_ws, size_t ws_size,
                              hipStream_t stream) {
  const float* email_x   = (const float*)d_in[0];
  const float* url_x     = (const float*)d_in[1];
  const float* sender_x  = (const float*)d_in[2];
  const float* W_email   = (const float*)d_in[3];
  const float* b_email   = (const float*)d_in[4];
  const float* url_bw    = (const float*)d_in[5];
  const float* url_sw    = (const float*)d_in[6];
  const float* snd_bw    = (const float*)d_in[7];
  const float* snd_sw    = (const float*)d_in[8];
  const float* Wl_se     = (const float*)d_in[9];
  const float* bl_se     = (const float*)d_in[10];
  const float* Wr_se     = (const float*)d_in[11];
  // d_in[12..14]: eu SAGE weights — dead code in the reference (result unused)
  const float* Wl_ue     = (const float*)d_in[15];
  const float* bl_ue     = (const float*)d_in[16];
  const float* Wr_ue     = (const float*)d_in[17];
  const float* bn_gamma  = (const float*)d_in[18];
  const float* bn_beta   = (const float*)d_in[19];
  const float* cls_bw    = (const float*)d_in[20];
  const float* cls_sw    = (const float*)d_in[21];
  const int*   se_src    = (const int*)d_in[22];
  const int*   se_dst    = (const int*)d_in[23];
  // d_in[24..25]: eu edges — dead
  const int*   ue_src    = (const int*)d_in[26];
  const int*   ue_dst    = (const int*)d_in[27];

  const int N_E = in_sizes[0] / 768;
  const int N_U = in_sizes[1] / 8;
  const int N_S = in_sizes[2];
  const int E_SE = in_sizes[22];
  const int E_UE = in_sizes[26];

  char* ws = (char*)d_ws;
  size_t off = 0;
  auto alloc = [&](size_t bytes) -> void* {
    void* p = ws + off;
    off = (off + bytes + 255) & ~(size_t)255;
    return p;
  };

  float* e      = (float*)alloc((size_t)N_E * H * 4);
  float* u      = (float*)alloc((size_t)N_U * H * 4);
  float* s      = (float*)alloc((size_t)N_S * H * 4);
  float* agg_s  = (float*)alloc((size_t)N_E * H * 4);
  float* agg_u  = (float*)alloc((size_t)N_E * H * 4);
  float* Wr_c   = (float*)alloc((size_t)H * H * 4);
  float* wpad_u = (float*)alloc((size_t)128 * 80 * 4);
  float* wpad_s = (float*)alloc((size_t)128 * 16 * 4);
  int* cnt_se   = (int*)alloc((size_t)N_E * 4);
  int* offs_se  = (int*)alloc(((size_t)N_E + 1) * 4);
  int* cur_se   = (int*)alloc((size_t)N_E * 4);
  int* srt_se   = (int*)alloc((size_t)E_SE * 4);
  int* cnt_ue   = (int*)alloc((size_t)N_E * 4);
  int* offs_ue  = (int*)alloc(((size_t)N_E + 1) * 4);
  int* cur_ue   = (int*)alloc((size_t)N_E * 4);
  int* srt_ue   = (int*)alloc((size_t)E_UE * 4);
  double* bnsum = (double*)alloc(512 * 8);
  float* scale  = (float*)alloc(256 * 4);
  float* shift  = (float*)alloc(256 * 4);
  // u is dead after aggregate_mean(ue); reuse its space for email_h
  float* eh = u;

  hipMemsetAsync(cnt_se, 0, (size_t)N_E * 4, stream);
  hipMemsetAsync(cnt_ue, 0, (size_t)N_E * 4, stream);
  hipMemsetAsync(bnsum, 0, 512 * 8, stream);

  // pack KAN weights (tiny)
  build_wpad<<<(128 * 80 + 255) / 256, 256, 0, stream>>>(url_bw, url_sw, wpad_u, 8, 80);
  build_wpad<<<(128 * 16 + 255) / 256, 256, 0, stream>>>(snd_bw, snd_sw, wpad_s, 1, 16);

  // node encoders
  gemm_n128<1, 1><<<(N_E + 31) / 32, 256, 0, stream>>>(
      N_E, 768, email_x, nullptr, nullptr, W_email, nullptr, nullptr, b_email, nullptr, e);
  kan_gemm<8><<<(N_U + 63) / 64, 256, 0, stream>>>(url_x, wpad_u, u, N_U);
  kan_gemm<1><<<(N_S + 63) / 64, 256, 0, stream>>>(sender_x, wpad_s, s, N_S);

  // CSR build for both email-destination edge sets
  count_kernel<<<(E_SE + 255) / 256, 256, 0, stream>>>(se_dst, E_SE, cnt_se);
  count_kernel<<<(E_UE + 255) / 256, 256, 0, stream>>>(ue_dst, E_UE, cnt_ue);
  scan_kernel<<<1, 1024, 0, stream>>>(cnt_se, N_E, offs_se, cur_se);
  scan_kernel<<<1, 1024, 0, stream>>>(cnt_ue, N_E, offs_ue, cur_ue);
  scatter_kernel<<<(E_SE + 255) / 256, 256, 0, stream>>>(se_src, se_dst, E_SE, cur_se, srt_se);
  scatter_kernel<<<(E_UE + 255) / 256, 256, 0, stream>>>(ue_src, ue_dst, E_UE, cur_ue, srt_ue);

  // mean aggregation (gather, no float atomics)
  aggregate_mean<<<(N_E + 3) / 4, 256, 0, stream>>>(s, offs_se, srt_se, agg_s, N_E);
  aggregate_mean<<<(N_E + 3) / 4, 256, 0, stream>>>(u, offs_ue, srt_ue, agg_u, N_E);

  // fused email_h = lrelu(0.5*(agg_s@Wl_se^T + agg_u@Wl_ue^T + e@(Wr_se+Wr_ue)^T + bl_se + bl_ue))
  add_mat<<<(H * H + 255) / 256, 256, 0, stream>>>(Wr_se, Wr_ue, Wr_c, H * H);
  gemm_n128<3, 2><<<(N_E + 31) / 32, 256, 0, stream>>>(
      N_E, 128, agg_s, agg_u, e, Wl_se, Wl_ue, Wr_c, bl_se, bl_ue, eh);

  // batchnorm over combined=[eh|e], then classifier KAN (BN fused into it)
  bn_stats<<<128, 256, 0, stream>>>(eh, e, N_E, bnsum);
  bn_finalize<<<1, 256, 0, stream>>>(bnsum, N_E, bn_gamma, bn_beta, scale, shift);
  classifier_kan<<<(N_E + 3) / 4, 256, 0, stream>>>(
      eh, e, scale, shift, cls_bw, cls_sw, (float*)d_out, N_E);
}

// Round 7
// 749.922 us; speedup vs baseline: 2.9206x; 1.0832x over previous
//
#include <hip/hip_runtime.h>
#include <hip/hip_bf16.h>
#include <math.h>

#define H 128

typedef __attribute__((ext_vector_type(8))) short short8;
typedef __attribute__((ext_vector_type(4))) float f32x4;

// ---------------------------------------------------------------- bf16 split helpers
__device__ __forceinline__ unsigned short f2bf(float f) {
  union { float f; unsigned u; } c{f};
  unsigned u = c.u;
  unsigned r = (u + 0x7FFFu + ((u >> 16) & 1u)) >> 16;  // round-nearest-even
  return (unsigned short)r;
}
__device__ __forceinline__ float bf2f(unsigned short h) {
  union { unsigned u; float f; } c{(unsigned)h << 16};
  return c.f;
}

// ---------------------------------------------------------------- B-splines
// grid[m] = (m-3)*0.4 - 1.0, m = 0..11  (G=5, K=3 -> 8 basis functions)
__device__ __forceinline__ float gridv(int m) { return (float)(m - 3) * 0.4f - 1.0f; }

__device__ __forceinline__ void bspline8(float x, float* b) {
  float t[11];
#pragma unroll
  for (int m = 0; m < 11; ++m)
    t[m] = (x >= gridv(m) && x < gridv(m + 1)) ? 1.0f : 0.0f;
#pragma unroll
  for (int j = 1; j <= 3; ++j) {
#pragma unroll
    for (int m = 0; m + j < 11; ++m) {
      float den1 = gridv(m + j) - gridv(m);
      float den2 = gridv(m + j + 1) - gridv(m + 1);
      t[m] = (x - gridv(m)) * (1.0f / den1) * t[m] +
             (gridv(m + j + 1) - x) * (1.0f / den2) * t[m + 1];
    }
  }
#pragma unroll
  for (int m = 0; m < 8; ++m) b[m] = t[m];
}

// ---------------------------------------------------------------- W fragment packing
// Pack W (128 out-cols x K) into MFMA B-fragment order, split bf16 hi/lo.
// Frag layout for mfma_f32_16x16x32_bf16 B-operand: lane l supplies
// col = l&15, k = (l>>4)*8 + j (j=0..7, 16B contiguous per lane).
// index(ks,cf,l,j) = (((ksBase+ks)*8 + cf)*64 + l)*8 + j
__global__ void pack_wfrag(const float* __restrict__ W0, const float* __restrict__ W1,
                           int K, int NS, unsigned short* __restrict__ WH,
                           unsigned short* __restrict__ WL, int ksBase) {
  int thr = blockIdx.x * blockDim.x + threadIdx.x;
  if (thr >= NS * 512) return;
  int ks = thr >> 9;
  int rem = thr & 511;
  int cf = rem >> 6;
  int l = rem & 63;
  int o = cf * 16 + (l & 15);
  size_t obase = (((size_t)(ksBase + ks) * 8 + cf) * 64 + l) * 8;
#pragma unroll
  for (int j = 0; j < 8; ++j) {
    int k = ks * 32 + ((l >> 4) << 3) + j;
    float v = W0[(size_t)o * K + k];
    if (W1) v += W1[(size_t)o * K + k];
    unsigned short hi = f2bf(v);
    unsigned short lo = f2bf(v - bf2f(hi));
    WH[obase + j] = hi;
    WL[obase + j] = lo;
  }
}

// ---------------------------------------------------------------- MFMA GEMM N=128
// out[M][128] = act( sum_seg A_seg(fp32) @ W_seg^T + bias0 (+bias1) )
// split-bf16: A = aH + aL, W = bH + bL; D += aH*bH + aH*bL + aL*bH.
// Block: 256 thr (4 waves), 32-row M-tile. Wave w owns cols [w*32, w*32+32).
// A staged fp32->bf16 hi/lo in LDS, padded row stride 40 ushorts (80B -> 2-way
// bank aliasing only). W read from fragment-packed global (L2-resident).
template <int NSEG, int KSPS, int ACT>
__global__ __launch_bounds__(256) void mfma_gemm(
    int M,
    const float* __restrict__ A0, const float* __restrict__ A1, const float* __restrict__ A2,
    const unsigned short* __restrict__ WH, const unsigned short* __restrict__ WL,
    const float* __restrict__ bias0, const float* __restrict__ bias1,
    float* __restrict__ out) {
  constexpr int SEGK = KSPS * 32;
  constexpr int NST = NSEG * KSPS;
  __shared__ __align__(16) unsigned short AsH[2][32 * 40];
  __shared__ __align__(16) unsigned short AsL[2][32 * 40];

  const int tid = threadIdx.x;
  const int w = tid >> 6;
  const int l = tid & 63;
  const int rowBase = blockIdx.x * 32;

  // cooperative A-load mapping: thread t -> row 0..31, k-offset (t&7)*4
  const int lr = tid >> 3;
  const int lk = (tid & 7) << 2;

  auto loadA = [&](int kst, float4& v) {
    int seg, kk;
    if (NSEG == 1) { seg = 0; kk = kst; }
    else { seg = kst / KSPS; kk = kst - seg * KSPS; }
    const float* Ap = (seg == 0) ? A0 : ((seg == 1) ? A1 : A2);
    int rg = rowBase + lr;
    if (rg < M) v = *(const float4*)(Ap + (size_t)rg * SEGK + kk * 32 + lk);
    else v = make_float4(0.f, 0.f, 0.f, 0.f);
  };
  auto writeA = [&](int buf, const float4& v) {
    float vv[4] = {v.x, v.y, v.z, v.w};
    ushort4 hh, ll;
    unsigned short* hp = (unsigned short*)&hh;
    unsigned short* lp = (unsigned short*)&ll;
#pragma unroll
    for (int i = 0; i < 4; ++i) {
      unsigned short hi = f2bf(vv[i]);
      hp[i] = hi;
      lp[i] = f2bf(vv[i] - bf2f(hi));
    }
    *(ushort4*)&AsH[buf][lr * 40 + lk] = hh;
    *(ushort4*)&AsL[buf][lr * 40 + lk] = ll;
  };

  f32x4 acc[2][2] = {};  // [row-frag][col-frag]

  float4 va;
  loadA(0, va);
  writeA(0, va);
  int cur = 0;

  const int fragOff = ((l >> 4) << 3);  // k-chunk within frag, in ushorts

  for (int kst = 0; kst < NST; ++kst) {
    // B frags for this k-step (global, fragment-packed, coalesced 16B/lane)
    short8 bH[2], bL[2];
#pragma unroll
    for (int c = 0; c < 2; ++c) {
      int cf = (w << 1) + c;
      size_t bi = (((size_t)kst * 8 + cf) * 64 + l) * 8;
      bH[c] = *(const short8*)(WH + bi);
      bL[c] = *(const short8*)(WL + bi);
    }
    float4 vn;
    if (kst + 1 < NST) loadA(kst + 1, vn);
    __syncthreads();
    // A frags: row-frag r covers rows r*16..r*16+15
    short8 aH[2], aL[2];
#pragma unroll
    for (int r = 0; r < 2; ++r) {
      int off = ((r << 4) + (l & 15)) * 40 + fragOff;
      aH[r] = *(const short8*)&AsH[cur][off];
      aL[r] = *(const short8*)&AsL[cur][off];
    }
#pragma unroll
    for (int r = 0; r < 2; ++r)
#pragma unroll
      for (int c = 0; c < 2; ++c) {
        acc[r][c] = __builtin_amdgcn_mfma_f32_16x16x32_bf16(aH[r], bH[c], acc[r][c], 0, 0, 0);
        acc[r][c] = __builtin_amdgcn_mfma_f32_16x16x32_bf16(aH[r], bL[c], acc[r][c], 0, 0, 0);
        acc[r][c] = __builtin_amdgcn_mfma_f32_16x16x32_bf16(aL[r], bH[c], acc[r][c], 0, 0, 0);
      }
    if (kst + 1 < NST) writeA(cur ^ 1, vn);
    cur ^= 1;
  }

  // C/D layout (m89/m91-verified): col = lane&15, row = (lane>>4)*4 + reg
#pragma unroll
  for (int r = 0; r < 2; ++r)
#pragma unroll
    for (int c = 0; c < 2; ++c) {
      int col = ((w << 1) + c) * 16 + (l & 15);
      float b0 = bias0[col];
      float b1 = bias1 ? bias1[col] : 0.f;
#pragma unroll
      for (int i = 0; i < 4; ++i) {
        int row = rowBase + (r << 4) + ((l >> 4) << 2) + i;
        if (row < M) {
          float x = acc[r][c][i] + b0;
          if (ACT == 1) {
            x = tanhf(x);
          } else {
            x = (x + b1) * 0.5f;
            x = (x >= 0.f) ? x : 0.2f * x;
          }
          out[(size_t)row * H + col] = x;
        }
      }
    }
}

// ---------------------------------------------------------------- pack KAN weights into padded [128][KP]
__global__ void build_wpad(const float* __restrict__ base_w, const float* __restrict__ spline_w,
                           float* __restrict__ Wpad, int D, int KP) {
  int idx = blockIdx.x * blockDim.x + threadIdx.x;
  if (idx >= 128 * KP) return;
  int o = idx / KP, k = idx - o * KP;
  float v = 0.f;
  if (k < D) v = base_w[o * D + k];
  else if (k < 9 * D) v = spline_w[o * D * 8 + (k - D)];
  Wpad[idx] = v;
}

// ---------------------------------------------------------------- fused KAN as GEMM (D inputs -> 128, tanh)
template <int D>
__global__ __launch_bounds__(256) void kan_gemm(
    const float* __restrict__ x, const float* __restrict__ Wpad,
    float* __restrict__ out, int N) {
  constexpr int KP = (9 * D + 15) & ~15;  // D=8 -> 80, D=1 -> 16
  __shared__ float As[KP][68];   // k-major persistent feature tile
  __shared__ float Bs[16][132];
  const int tid = threadIdx.x;
  const int rowBase = blockIdx.x * 64;

  // feature fill: one (node, input) pair per item
  for (int idx = tid; idx < 64 * D; idx += 256) {
    int nl = idx / D, i = idx - nl * D;
    int n = rowBase + nl;
    float xv = (n < N) ? x[(size_t)n * D + i] : 0.f;
    float sg = 1.f / (1.f + expf(-xv));
    float b[8];
    bspline8(xv, b);
    As[i][nl] = xv * sg;
#pragma unroll
    for (int m = 0; m < 8; ++m) As[D + i * 8 + m][nl] = b[m];
  }
  // zero the pad rows (k = 9D .. KP-1)
  for (int idx = tid; idx < (KP - 9 * D) * 64; idx += 256) {
    int r = idx >> 6, c = idx & 63;
    As[9 * D + r][c] = 0.f;
  }

  const int rb = (tid >> 5) << 3;
  const int cb = (tid & 31) << 2;
  const int bo = tid >> 1;
  const int bk = (tid & 1) << 3;
  float acc[8][4] = {};

  for (int kc = 0; kc < KP / 16; ++kc) {
    int koff = kc << 4;
    float4 bv0 = *(const float4*)(Wpad + (size_t)bo * KP + koff + bk);
    float4 bv1 = *(const float4*)(Wpad + (size_t)bo * KP + koff + bk + 4);
    __syncthreads();  // (kc==0: also covers feature fill)
    Bs[bk + 0][bo] = bv0.x; Bs[bk + 1][bo] = bv0.y; Bs[bk + 2][bo] = bv0.z; Bs[bk + 3][bo] = bv0.w;
    Bs[bk + 4][bo] = bv1.x; Bs[bk + 5][bo] = bv1.y; Bs[bk + 6][bo] = bv1.z; Bs[bk + 7][bo] = bv1.w;
    __syncthreads();
#pragma unroll
    for (int k = 0; k < 16; ++k) {
      float4 a0 = *(const float4*)&As[koff + k][rb];
      float4 a1 = *(const float4*)&As[koff + k][rb + 4];
      float4 b = *(const float4*)&Bs[k][cb];
      float a[8] = {a0.x, a0.y, a0.z, a0.w, a1.x, a1.y, a1.z, a1.w};
      float bb[4] = {b.x, b.y, b.z, b.w};
#pragma unroll
      for (int r = 0; r < 8; ++r)
#pragma unroll
        for (int c = 0; c < 4; ++c) acc[r][c] += a[r] * bb[c];
    }
  }

#pragma unroll
  for (int r = 0; r < 8; ++r) {
    int n = rowBase + rb + r;
    if (n < N) {
      float v[4] = {tanhf(acc[r][0]), tanhf(acc[r][1]), tanhf(acc[r][2]), tanhf(acc[r][3])};
      *(float4*)(out + (size_t)n * H + cb) = *(float4*)v;
    }
  }
}

// ---------------------------------------------------------------- CSR build
__global__ void count_kernel(const int* __restrict__ dst, int E, int* __restrict__ cnt) {
  int i = blockIdx.x * blockDim.x + threadIdx.x;
  if (i < E) atomicAdd(&cnt[dst[i]], 1);
}

// single-block scan, wave-shuffle based
__global__ __launch_bounds__(1024) void scan_kernel(
    const int* __restrict__ cnt, int n, int* __restrict__ offs, int* __restrict__ cursor) {
  __shared__ int wsum[16];
  __shared__ int carry_s;
  const int tid = threadIdx.x;
  const int lane = tid & 63;
  const int wid = tid >> 6;
  if (tid == 0) carry_s = 0;
  __syncthreads();
  for (int base = 0; base < n; base += 1024) {
    int i = base + tid;
    int v = (i < n) ? cnt[i] : 0;
    int x = v;
#pragma unroll
    for (int off = 1; off < 64; off <<= 1) {
      int t = __shfl_up(x, off);
      if (lane >= off) x += t;
    }
    if (lane == 63) wsum[wid] = x;
    __syncthreads();
    if (wid == 0) {
      int w = (lane < 16) ? wsum[lane] : 0;
#pragma unroll
      for (int off = 1; off < 16; off <<= 1) {
        int t = __shfl_up(w, off);
        if (lane >= off) w += t;
      }
      if (lane < 16) wsum[lane] = w;
    }
    __syncthreads();
    int waveoff = (wid == 0) ? 0 : wsum[wid - 1];
    int excl = carry_s + waveoff + (x - v);
    if (i < n) { offs[i] = excl; cursor[i] = excl; }
    int total = wsum[15];
    __syncthreads();
    if (tid == 0) carry_s += total;
    __syncthreads();
  }
  if (threadIdx.x == 0) offs[n] = carry_s;
}

__global__ void scatter_kernel(const int* __restrict__ src, const int* __restrict__ dst, int E,
                               int* __restrict__ cursor, int* __restrict__ sorted_src) {
  int i = blockIdx.x * blockDim.x + threadIdx.x;
  if (i < E) {
    int p = atomicAdd(&cursor[dst[i]], 1);
    sorted_src[p] = src[i];
  }
}

// mean aggregation: one wave per destination node, float2 lanes, 2-deep MLP
__global__ __launch_bounds__(256) void aggregate_mean(
    const float* __restrict__ feat, const int* __restrict__ offs,
    const int* __restrict__ sorted_src, float* __restrict__ agg, int n_dst) {
  int d = (blockIdx.x << 2) + (threadIdx.x >> 6);
  if (d >= n_dst) return;
  int lane = threadIdx.x & 63;
  int s0 = offs[d], s1 = offs[d + 1];
  float ax = 0.f, ay = 0.f;
  const float* base = feat + (lane << 1);
  int k = s0;
  for (; k + 1 < s1; k += 2) {
    int i0 = sorted_src[k];
    int i1 = sorted_src[k + 1];
    float2 v0 = *(const float2*)(base + (size_t)i0 * H);
    float2 v1 = *(const float2*)(base + (size_t)i1 * H);
    ax += v0.x + v1.x;
    ay += v0.y + v1.y;
  }
  if (k < s1) {
    int i0 = sorted_src[k];
    float2 v0 = *(const float2*)(base + (size_t)i0 * H);
    ax += v0.x;
    ay += v0.y;
  }
  float inv = 1.f / fmaxf((float)(s1 - s0), 1.f);
  *(float2*)(agg + (size_t)d * H + (lane << 1)) = make_float2(ax * inv, ay * inv);
}

// ---------------------------------------------------------------- BatchNorm stats (combined = [eh | e])
__global__ void bn_stats(const float* __restrict__ eh, const float* __restrict__ e, int M,
                         double* __restrict__ sums) {
  int t = threadIdx.x;  // 256 = channel
  double s = 0.0, s2 = 0.0;
  for (int r = blockIdx.x; r < M; r += gridDim.x) {
    float v = (t < 128) ? eh[(size_t)r * 128 + t] : e[(size_t)r * 128 + (t - 128)];
    s += v;
    s2 += (double)v * v;
  }
  atomicAdd(&sums[t], s);
  atomicAdd(&sums[256 + t], s2);
}

__global__ void bn_finalize(const double* __restrict__ sums, int M,
                            const float* __restrict__ gamma, const float* __restrict__ beta,
                            float* __restrict__ scale, float* __restrict__ shift) {
  int c = threadIdx.x;
  if (c < 256) {
    double mu = sums[c] / M;
    double var = sums[256 + c] / M - mu * mu;
    float rstd = 1.0f / sqrtf((float)var + 1e-5f);
    float g = gamma[c] * rstd;
    scale[c] = g;
    shift[c] = beta[c] - (float)mu * g;
  }
}

// ---------------------------------------------------------------- classifier KAN (256 -> 2), BN fused
__global__ __launch_bounds__(256) void classifier_kan(
    const float* __restrict__ eh, const float* __restrict__ e,
    const float* __restrict__ scale, const float* __restrict__ shift,
    const float* __restrict__ base_w, const float* __restrict__ spline_w,
    float* __restrict__ out, int M) {
  __shared__ float wT[18][256];  // [2 base + 16 spline][channel]
  __shared__ float sc[256], sh[256];
  int tid = threadIdx.x;
  for (int idx = tid; idx < 18 * 256; idx += 256) {
    int k = idx >> 8, c = idx & 255;
    float v;
    if (k < 2) v = base_w[k * 256 + c];
    else {
      int kk = k - 2, o = kk >> 3, b = kk & 7;
      v = spline_w[((size_t)o * 256 + c) * 8 + b];
    }
    wT[k][c] = v;
  }
  sc[tid] = scale[tid];
  sh[tid] = shift[tid];
  __syncthreads();
  int wave = tid >> 6, lane = tid & 63;
  int r = blockIdx.x * 4 + wave;
  if (r >= M) return;
  float a0 = 0.f, a1 = 0.f;
#pragma unroll
  for (int m = 0; m < 4; ++m) {
    int c = lane + (m << 6);
    float xv = (c < 128) ? eh[(size_t)r * 128 + c] : e[(size_t)r * 128 + (c - 128)];
    float y = xv * sc[c] + sh[c];
    float sg = 1.f / (1.f + expf(-y));
    float si = y * sg;
    float b[8];
    bspline8(y, b);
    a0 += si * wT[0][c];
    a1 += si * wT[1][c];
#pragma unroll
    for (int bb = 0; bb < 8; ++bb) {
      a0 += b[bb] * wT[2 + bb][c];
      a1 += b[bb] * wT[10 + bb][c];
    }
  }
#pragma unroll
  for (int off = 32; off >= 1; off >>= 1) {
    a0 += __shfl_down(a0, off);
    a1 += __shfl_down(a1, off);
  }
  if (lane == 0) {
    out[(size_t)r * 2] = a0;
    out[(size_t)r * 2 + 1] = a1;
  }
}

// ---------------------------------------------------------------- launch
extern "C" void kernel_launch(void* const* d_in, const int* in_sizes, int n_in,
                              void* d_out, int out_size, void* d_ws, size_t ws_size,
                              hipStream_t stream) {
  const float* email_x   = (const float*)d_in[0];
  const float* url_x     = (const float*)d_in[1];
  const float* sender_x  = (const float*)d_in[2];
  const float* W_email   = (const float*)d_in[3];
  const float* b_email   = (const float*)d_in[4];
  const float* url_bw    = (const float*)d_in[5];
  const float* url_sw    = (const float*)d_in[6];
  const float* snd_bw    = (const float*)d_in[7];
  const float* snd_sw    = (const float*)d_in[8];
  const float* Wl_se     = (const float*)d_in[9];
  const float* bl_se     = (const float*)d_in[10];
  const float* Wr_se     = (const float*)d_in[11];
  // d_in[12..14]: eu SAGE weights — dead code in the reference (result unused)
  const float* Wl_ue     = (const float*)d_in[15];
  const float* bl_ue     = (const float*)d_in[16];
  const float* Wr_ue     = (const float*)d_in[17];
  const float* bn_gamma  = (const float*)d_in[18];
  const float* bn_beta   = (const float*)d_in[19];
  const float* cls_bw    = (const float*)d_in[20];
  const float* cls_sw    = (const float*)d_in[21];
  const int*   se_src    = (const int*)d_in[22];
  const int*   se_dst    = (const int*)d_in[23];
  // d_in[24..25]: eu edges — dead
  const int*   ue_src    = (const int*)d_in[26];
  const int*   ue_dst    = (const int*)d_in[27];

  const int N_E = in_sizes[0] / 768;
  const int N_U = in_sizes[1] / 8;
  const int N_S = in_sizes[2];
  const int E_SE = in_sizes[22];
  const int E_UE = in_sizes[26];

  char* ws = (char*)d_ws;
  size_t off = 0;
  auto alloc = [&](size_t bytes) -> void* {
    void* p = ws + off;
    off = (off + bytes + 255) & ~(size_t)255;
    return p;
  };

  float* e      = (float*)alloc((size_t)N_E * H * 4);
  float* u      = (float*)alloc((size_t)N_U * H * 4);
  float* s      = (float*)alloc((size_t)N_S * H * 4);
  float* agg_s  = (float*)alloc((size_t)N_E * H * 4);
  float* agg_u  = (float*)alloc((size_t)N_E * H * 4);
  float* wpad_u = (float*)alloc((size_t)128 * 80 * 4);
  float* wpad_s = (float*)alloc((size_t)128 * 16 * 4);
  // MFMA fragment-packed weights (split bf16 hi/lo)
  unsigned short* wEH = (unsigned short*)alloc((size_t)24 * 8 * 64 * 8 * 2);
  unsigned short* wEL = (unsigned short*)alloc((size_t)24 * 8 * 64 * 8 * 2);
  unsigned short* wHH = (unsigned short*)alloc((size_t)12 * 8 * 64 * 8 * 2);
  unsigned short* wHL = (unsigned short*)alloc((size_t)12 * 8 * 64 * 8 * 2);
  int* cnt_se   = (int*)alloc((size_t)N_E * 4);
  int* offs_se  = (int*)alloc(((size_t)N_E + 1) * 4);
  int* cur_se   = (int*)alloc((size_t)N_E * 4);
  int* srt_se   = (int*)alloc((size_t)E_SE * 4);
  int* cnt_ue   = (int*)alloc((size_t)N_E * 4);
  int* offs_ue  = (int*)alloc(((size_t)N_E + 1) * 4);
  int* cur_ue   = (int*)alloc((size_t)N_E * 4);
  int* srt_ue   = (int*)alloc((size_t)E_UE * 4);
  double* bnsum = (double*)alloc(512 * 8);
  float* scale  = (float*)alloc(256 * 4);
  float* shift  = (float*)alloc(256 * 4);
  // u is dead after aggregate_mean(ue); reuse its space for email_h
  float* eh = u;

  hipMemsetAsync(cnt_se, 0, (size_t)N_E * 4, stream);
  hipMemsetAsync(cnt_ue, 0, (size_t)N_E * 4, stream);
  hipMemsetAsync(bnsum, 0, 512 * 8, stream);

  // pack weights (tiny)
  build_wpad<<<(128 * 80 + 255) / 256, 256, 0, stream>>>(url_bw, url_sw, wpad_u, 8, 80);
  build_wpad<<<(128 * 16 + 255) / 256, 256, 0, stream>>>(snd_bw, snd_sw, wpad_s, 1, 16);
  pack_wfrag<<<(24 * 512 + 255) / 256, 256, 0, stream>>>(W_email, nullptr, 768, 24, wEH, wEL, 0);
  pack_wfrag<<<(4 * 512 + 255) / 256, 256, 0, stream>>>(Wl_se, nullptr, 128, 4, wHH, wHL, 0);
  pack_wfrag<<<(4 * 512 + 255) / 256, 256, 0, stream>>>(Wl_ue, nullptr, 128, 4, wHH, wHL, 4);
  pack_wfrag<<<(4 * 512 + 255) / 256, 256, 0, stream>>>(Wr_se, Wr_ue, 128, 4, wHH, wHL, 8);

  // node encoders
  mfma_gemm<1, 24, 1><<<(N_E + 31) / 32, 256, 0, stream>>>(
      N_E, email_x, nullptr, nullptr, wEH, wEL, b_email, nullptr, e);
  kan_gemm<8><<<(N_U + 63) / 64, 256, 0, stream>>>(url_x, wpad_u, u, N_U);
  kan_gemm<1><<<(N_S + 63) / 64, 256, 0, stream>>>(sender_x, wpad_s, s, N_S);

  // CSR build for both email-destination edge sets
  count_kernel<<<(E_SE + 255) / 256, 256, 0, stream>>>(se_dst, E_SE, cnt_se);
  count_kernel<<<(E_UE + 255) / 256, 256, 0, stream>>>(ue_dst, E_UE, cnt_ue);
  scan_kernel<<<1, 1024, 0, stream>>>(cnt_se, N_E, offs_se, cur_se);
  scan_kernel<<<1, 1024, 0, stream>>>(cnt_ue, N_E, offs_ue, cur_ue);
  scatter_kernel<<<(E_SE + 255) / 256, 256, 0, stream>>>(se_src, se_dst, E_SE, cur_se, srt_se);
  scatter_kernel<<<(E_UE + 255) / 256, 256, 0, stream>>>(ue_src, ue_dst, E_UE, cur_ue, srt_ue);

  // mean aggregation (gather, no float atomics)
  aggregate_mean<<<(N_E + 3) / 4, 256, 0, stream>>>(s, offs_se, srt_se, agg_s, N_E);
  aggregate_mean<<<(N_E + 3) / 4, 256, 0, stream>>>(u, offs_ue, srt_ue, agg_u, N_E);

  // fused email_h = lrelu(0.5*(agg_s@Wl_se^T + agg_u@Wl_ue^T + e@(Wr_se+Wr_ue)^T + bl_se + bl_ue))
  mfma_gemm<3, 4, 2><<<(N_E + 31) / 32, 256, 0, stream>>>(
      N_E, agg_s, agg_u, e, wHH, wHL, bl_se, bl_ue, eh);

  // batchnorm over combined=[eh|e], then classifier KAN (BN fused into it)
  bn_stats<<<128, 256, 0, stream>>>(eh, e, N_E, bnsum);
  bn_finalize<<<1, 256, 0, stream>>>(bnsum, N_E, bn_gamma, bn_beta, scale, shift);
  classifier_kan<<<(N_E + 3) / 4, 256, 0, stream>>>(
      eh, e, scale, shift, cls_bw, cls_sw, (float*)d_out, N_E);
}

// Round 8
// 656.309 us; speedup vs baseline: 3.3372x; 1.1426x over previous
//
#include <hip/hip_runtime.h>
#include <hip/hip_bf16.h>
#include <hip/hip_fp16.h>
#include <math.h>

#define H 128

typedef __attribute__((ext_vector_type(8))) short short8;
typedef __attribute__((ext_vector_type(4))) float f32x4;

// ---------------------------------------------------------------- bf16 split helpers
__device__ __forceinline__ unsigned short f2bf(float f) {
  union { float f; unsigned u; } c{f};
  unsigned u = c.u;
  unsigned r = (u + 0x7FFFu + ((u >> 16) & 1u)) >> 16;  // round-nearest-even
  return (unsigned short)r;
}
__device__ __forceinline__ float bf2f(unsigned short h) {
  union { unsigned u; float f; } c{(unsigned)h << 16};
  return c.f;
}
__device__ __forceinline__ void splitHL(float v, unsigned short& hi, unsigned short& lo) {
  hi = f2bf(v);
  lo = f2bf(v - bf2f(hi));
}

// ---------------------------------------------------------------- B-splines
// grid[m] = (m-3)*0.4 - 1.0, m = 0..11  (G=5, K=3 -> 8 basis functions)
__device__ __forceinline__ float gridv(int m) { return (float)(m - 3) * 0.4f - 1.0f; }

// full Cox-de Boor (used only in tiny sender KAN)
__device__ __forceinline__ void bspline8(float x, float* b) {
  float t[11];
#pragma unroll
  for (int m = 0; m < 11; ++m)
    t[m] = (x >= gridv(m) && x < gridv(m + 1)) ? 1.0f : 0.0f;
#pragma unroll
  for (int j = 1; j <= 3; ++j) {
#pragma unroll
    for (int m = 0; m + j < 11; ++m) {
      float den1 = gridv(m + j) - gridv(m);
      float den2 = gridv(m + j + 1) - gridv(m + 1);
      t[m] = (x - gridv(m)) * (1.0f / den1) * t[m] +
             (gridv(m + j + 1) - x) * (1.0f / den2) * t[m + 1];
    }
  }
#pragma unroll
  for (int m = 0; m < 8; ++m) b[m] = t[m];
}

// closed-form uniform cubic B-spline pieces: for x in [g(i),g(i+1)),
// basis m = i-k has value P[k](u), u = (x-g(i))/h. P0=u^3/6 ... P3=(1-u)^3/6.
__device__ __forceinline__ void spline_pieces(float x, int& i0, float& P0, float& P1,
                                              float& P2, float& P3) {
  float xs = (x + 2.2f) * 2.5f;
  float fi = floorf(xs);
  float u = xs - fi;
  i0 = (int)fi;
  float u2 = u * u, u3 = u2 * u;
  P0 = u3 * (1.f / 6.f);
  P1 = (1.f + 3.f * (u + u2 - u3)) * (1.f / 6.f);
  P2 = (4.f - 6.f * u2 + 3.f * u3) * (1.f / 6.f);
  float um = 1.f - u;
  P3 = um * um * um * (1.f / 6.f);
}

// ---------------------------------------------------------------- W fragment packing
// (hardware-verified in round 7) B-frag: lane l -> col l&15, k = (l>>4)*8 + j.
__global__ void pack_wfrag(const float* __restrict__ W0, const float* __restrict__ W1,
                           int K, int NS, unsigned short* __restrict__ WH,
                           unsigned short* __restrict__ WL, int ksBase) {
  int thr = blockIdx.x * blockDim.x + threadIdx.x;
  if (thr >= NS * 512) return;
  int ks = thr >> 9;
  int rem = thr & 511;
  int cf = rem >> 6;
  int l = rem & 63;
  int o = cf * 16 + (l & 15);
  size_t obase = (((size_t)(ksBase + ks) * 8 + cf) * 64 + l) * 8;
#pragma unroll
  for (int j = 0; j < 8; ++j) {
    int k = ks * 32 + ((l >> 4) << 3) + j;
    float v = W0[(size_t)o * K + k];
    if (W1) v += W1[(size_t)o * K + k];
    unsigned short hi, lo;
    splitHL(v, hi, lo);
    WH[obase + j] = hi;
    WL[obase + j] = lo;
  }
}

// zero-padded variant: source has Kreal cols, packed K = NS*32 (pad with 0)
__global__ void pack_wfrag_pad(const float* __restrict__ W0, int Kreal, int NS,
                               unsigned short* __restrict__ WH,
                               unsigned short* __restrict__ WL) {
  int thr = blockIdx.x * blockDim.x + threadIdx.x;
  if (thr >= NS * 512) return;
  int ks = thr >> 9;
  int rem = thr & 511;
  int cf = rem >> 6;
  int l = rem & 63;
  int o = cf * 16 + (l & 15);
  size_t obase = (((size_t)ks * 8 + cf) * 64 + l) * 8;
#pragma unroll
  for (int j = 0; j < 8; ++j) {
    int k = ks * 32 + ((l >> 4) << 3) + j;
    float v = (k < Kreal) ? W0[(size_t)o * Kreal + k] : 0.f;
    unsigned short hi, lo;
    splitHL(v, hi, lo);
    WH[obase + j] = hi;
    WL[obase + j] = lo;
  }
}

// ---------------------------------------------------------------- MFMA GEMM N=128 (HW-verified round 7)
template <int NSEG, int KSPS, int ACT>
__global__ __launch_bounds__(256) void mfma_gemm(
    int M,
    const float* __restrict__ A0, const float* __restrict__ A1, const float* __restrict__ A2,
    const unsigned short* __restrict__ WH, const unsigned short* __restrict__ WL,
    const float* __restrict__ bias0, const float* __restrict__ bias1,
    float* __restrict__ out) {
  constexpr int SEGK = KSPS * 32;
  constexpr int NST = NSEG * KSPS;
  __shared__ __align__(16) unsigned short AsH[2][32 * 40];
  __shared__ __align__(16) unsigned short AsL[2][32 * 40];

  const int tid = threadIdx.x;
  const int w = tid >> 6;
  const int l = tid & 63;
  const int rowBase = blockIdx.x * 32;

  const int lr = tid >> 3;
  const int lk = (tid & 7) << 2;

  auto loadA = [&](int kst, float4& v) {
    int seg, kk;
    if (NSEG == 1) { seg = 0; kk = kst; }
    else { seg = kst / KSPS; kk = kst - seg * KSPS; }
    const float* Ap = (seg == 0) ? A0 : ((seg == 1) ? A1 : A2);
    int rg = rowBase + lr;
    if (rg < M) v = *(const float4*)(Ap + (size_t)rg * SEGK + kk * 32 + lk);
    else v = make_float4(0.f, 0.f, 0.f, 0.f);
  };
  auto writeA = [&](int buf, const float4& v) {
    float vv[4] = {v.x, v.y, v.z, v.w};
    ushort4 hh, ll;
    unsigned short* hp = (unsigned short*)&hh;
    unsigned short* lp = (unsigned short*)&ll;
#pragma unroll
    for (int i = 0; i < 4; ++i) splitHL(vv[i], hp[i], lp[i]);
    *(ushort4*)&AsH[buf][lr * 40 + lk] = hh;
    *(ushort4*)&AsL[buf][lr * 40 + lk] = ll;
  };

  f32x4 acc[2][2] = {};

  float4 va;
  loadA(0, va);
  writeA(0, va);
  int cur = 0;

  const int fragOff = ((l >> 4) << 3);

  for (int kst = 0; kst < NST; ++kst) {
    short8 bH[2], bL[2];
#pragma unroll
    for (int c = 0; c < 2; ++c) {
      int cf = (w << 1) + c;
      size_t bi = (((size_t)kst * 8 + cf) * 64 + l) * 8;
      bH[c] = *(const short8*)(WH + bi);
      bL[c] = *(const short8*)(WL + bi);
    }
    float4 vn;
    if (kst + 1 < NST) loadA(kst + 1, vn);
    __syncthreads();
    short8 aH[2], aL[2];
#pragma unroll
    for (int r = 0; r < 2; ++r) {
      int off = ((r << 4) + (l & 15)) * 40 + fragOff;
      aH[r] = *(const short8*)&AsH[cur][off];
      aL[r] = *(const short8*)&AsL[cur][off];
    }
#pragma unroll
    for (int r = 0; r < 2; ++r)
#pragma unroll
      for (int c = 0; c < 2; ++c) {
        acc[r][c] = __builtin_amdgcn_mfma_f32_16x16x32_bf16(aH[r], bH[c], acc[r][c], 0, 0, 0);
        acc[r][c] = __builtin_amdgcn_mfma_f32_16x16x32_bf16(aH[r], bL[c], acc[r][c], 0, 0, 0);
        acc[r][c] = __builtin_amdgcn_mfma_f32_16x16x32_bf16(aL[r], bH[c], acc[r][c], 0, 0, 0);
      }
    if (kst + 1 < NST) writeA(cur ^ 1, vn);
    cur ^= 1;
  }

#pragma unroll
  for (int r = 0; r < 2; ++r)
#pragma unroll
    for (int c = 0; c < 2; ++c) {
      int col = ((w << 1) + c) * 16 + (l & 15);
      float b0 = bias0[col];
      float b1 = bias1 ? bias1[col] : 0.f;
#pragma unroll
      for (int i = 0; i < 4; ++i) {
        int row = rowBase + (r << 4) + ((l >> 4) << 2) + i;
        if (row < M) {
          float x = acc[r][c][i] + b0;
          if (ACT == 1) {
            x = tanhf(x);
          } else {
            x = (x + b1) * 0.5f;
            x = (x >= 0.f) ? x : 0.2f * x;
          }
          out[(size_t)row * H + col] = x;
        }
      }
    }
}

// ---------------------------------------------------------------- url KAN as MFMA GEMM
// 32-node tile. Features (silu + 8 closed-form bases per input, 72 total,
// padded to K=96 = 3 k-steps) computed once into split-bf16 LDS.
// B from fragment-packed wpad_u (zero-padded). Output tanh -> fp16.
__global__ __launch_bounds__(256) void kan_mfma8(
    const float* __restrict__ x, const unsigned short* __restrict__ WH,
    const unsigned short* __restrict__ WL, unsigned short* __restrict__ out, int N) {
  constexpr int RS = 104;  // row stride in ushorts (208 B, 16B-aligned, ~2-way banks)
  __shared__ __align__(16) unsigned short AsH[32 * RS];
  __shared__ __align__(16) unsigned short AsL[32 * RS];
  const int tid = threadIdx.x;
  const int w = tid >> 6;
  const int l = tid & 63;
  const int rowBase = blockIdx.x * 32;

  // zero pad region k = 72..95
  for (int idx = tid; idx < 32 * 24; idx += 256) {
    int r = idx / 24, k = 72 + idx - (idx / 24) * 24;
    AsH[r * RS + k] = 0;
    AsL[r * RS + k] = 0;
  }
  // feature fill: one (node, input) pair per thread
  {
    int nl = tid >> 3, i = tid & 7;
    int n = rowBase + nl;
    float xv = (n < N) ? x[(size_t)n * 8 + i] : 0.f;
    float sg = 1.f / (1.f + expf(-xv));
    float si = xv * sg;
    unsigned short hi, lo;
    splitHL(si, hi, lo);
    AsH[nl * RS + i] = hi;
    AsL[nl * RS + i] = lo;
    int i0;
    float P0, P1, P2, P3;
    spline_pieces(xv, i0, P0, P1, P2, P3);
#pragma unroll
    for (int m = 0; m < 8; ++m) {
      int d = i0 - m;
      float b = (d == 0) ? P0 : (d == 1) ? P1 : (d == 2) ? P2 : (d == 3) ? P3 : 0.f;
      splitHL(b, hi, lo);
      AsH[nl * RS + 8 + i * 8 + m] = hi;
      AsL[nl * RS + 8 + i * 8 + m] = lo;
    }
  }
  __syncthreads();

  f32x4 acc[2][2] = {};
  const int fragOff = ((l >> 4) << 3);
#pragma unroll
  for (int kst = 0; kst < 3; ++kst) {
    short8 bH[2], bL[2];
#pragma unroll
    for (int c = 0; c < 2; ++c) {
      int cf = (w << 1) + c;
      size_t bi = (((size_t)kst * 8 + cf) * 64 + l) * 8;
      bH[c] = *(const short8*)(WH + bi);
      bL[c] = *(const short8*)(WL + bi);
    }
    short8 aH[2], aL[2];
#pragma unroll
    for (int r = 0; r < 2; ++r) {
      int off = ((r << 4) + (l & 15)) * RS + kst * 32 + fragOff;
      aH[r] = *(const short8*)&AsH[off];
      aL[r] = *(const short8*)&AsL[off];
    }
#pragma unroll
    for (int r = 0; r < 2; ++r)
#pragma unroll
      for (int c = 0; c < 2; ++c) {
        acc[r][c] = __builtin_amdgcn_mfma_f32_16x16x32_bf16(aH[r], bH[c], acc[r][c], 0, 0, 0);
        acc[r][c] = __builtin_amdgcn_mfma_f32_16x16x32_bf16(aH[r], bL[c], acc[r][c], 0, 0, 0);
        acc[r][c] = __builtin_amdgcn_mfma_f32_16x16x32_bf16(aL[r], bH[c], acc[r][c], 0, 0, 0);
      }
  }

#pragma unroll
  for (int r = 0; r < 2; ++r)
#pragma unroll
    for (int c = 0; c < 2; ++c) {
      int col = ((w << 1) + c) * 16 + (l & 15);
#pragma unroll
      for (int i = 0; i < 4; ++i) {
        int row = rowBase + (r << 4) + ((l >> 4) << 2) + i;
        if (row < N) {
          float v = tanhf(acc[r][c][i]);
          out[(size_t)row * H + col] = __half_as_ushort(__float2half(v));
        }
      }
    }
}

// ---------------------------------------------------------------- pack KAN weights into padded [128][KP]
__global__ void build_wpad(const float* __restrict__ base_w, const float* __restrict__ spline_w,
                           float* __restrict__ Wpad, int D, int KP) {
  int idx = blockIdx.x * blockDim.x + threadIdx.x;
  if (idx >= 128 * KP) return;
  int o = idx / KP, k = idx - o * KP;
  float v = 0.f;
  if (k < D) v = base_w[o * D + k];
  else if (k < 9 * D) v = spline_w[o * D * 8 + (k - D)];
  Wpad[idx] = v;
}

// ---------------------------------------------------------------- small fused KAN (sender, D=1)
template <int D>
__global__ __launch_bounds__(256) void kan_gemm(
    const float* __restrict__ x, const float* __restrict__ Wpad,
    float* __restrict__ out, int N) {
  constexpr int KP = (9 * D + 15) & ~15;
  __shared__ float As[KP][68];
  __shared__ float Bs[16][132];
  const int tid = threadIdx.x;
  const int rowBase = blockIdx.x * 64;

  for (int idx = tid; idx < 64 * D; idx += 256) {
    int nl = idx / D, i = idx - nl * D;
    int n = rowBase + nl;
    float xv = (n < N) ? x[(size_t)n * D + i] : 0.f;
    float sg = 1.f / (1.f + expf(-xv));
    float b[8];
    bspline8(xv, b);
    As[i][nl] = xv * sg;
#pragma unroll
    for (int m = 0; m < 8; ++m) As[D + i * 8 + m][nl] = b[m];
  }
  for (int idx = tid; idx < (KP - 9 * D) * 64; idx += 256) {
    int r = idx >> 6, c = idx & 63;
    As[9 * D + r][c] = 0.f;
  }

  const int rb = (tid >> 5) << 3;
  const int cb = (tid & 31) << 2;
  const int bo = tid >> 1;
  const int bk = (tid & 1) << 3;
  float acc[8][4] = {};

  for (int kc = 0; kc < KP / 16; ++kc) {
    int koff = kc << 4;
    float4 bv0 = *(const float4*)(Wpad + (size_t)bo * KP + koff + bk);
    float4 bv1 = *(const float4*)(Wpad + (size_t)bo * KP + koff + bk + 4);
    __syncthreads();
    Bs[bk + 0][bo] = bv0.x; Bs[bk + 1][bo] = bv0.y; Bs[bk + 2][bo] = bv0.z; Bs[bk + 3][bo] = bv0.w;
    Bs[bk + 4][bo] = bv1.x; Bs[bk + 5][bo] = bv1.y; Bs[bk + 6][bo] = bv1.z; Bs[bk + 7][bo] = bv1.w;
    __syncthreads();
#pragma unroll
    for (int k = 0; k < 16; ++k) {
      float4 a0 = *(const float4*)&As[koff + k][rb];
      float4 a1 = *(const float4*)&As[koff + k][rb + 4];
      float4 b = *(const float4*)&Bs[k][cb];
      float a[8] = {a0.x, a0.y, a0.z, a0.w, a1.x, a1.y, a1.z, a1.w};
      float bb[4] = {b.x, b.y, b.z, b.w};
#pragma unroll
      for (int r = 0; r < 8; ++r)
#pragma unroll
        for (int c = 0; c < 4; ++c) acc[r][c] += a[r] * bb[c];
    }
  }

#pragma unroll
  for (int r = 0; r < 8; ++r) {
    int n = rowBase + rb + r;
    if (n < N) {
      float v[4] = {tanhf(acc[r][0]), tanhf(acc[r][1]), tanhf(acc[r][2]), tanhf(acc[r][3])};
      *(float4*)(out + (size_t)n * H + cb) = *(float4*)v;
    }
  }
}

// ---------------------------------------------------------------- CSR build
__global__ void count_kernel(const int* __restrict__ dst, int E, int* __restrict__ cnt) {
  int i = blockIdx.x * blockDim.x + threadIdx.x;
  if (i < E) atomicAdd(&cnt[dst[i]], 1);
}

__global__ __launch_bounds__(1024) void scan_kernel(
    const int* __restrict__ cnt, int n, int* __restrict__ offs, int* __restrict__ cursor) {
  __shared__ int wsum[16];
  __shared__ int carry_s;
  const int tid = threadIdx.x;
  const int lane = tid & 63;
  const int wid = tid >> 6;
  if (tid == 0) carry_s = 0;
  __syncthreads();
  for (int base = 0; base < n; base += 1024) {
    int i = base + tid;
    int v = (i < n) ? cnt[i] : 0;
    int x = v;
#pragma unroll
    for (int off = 1; off < 64; off <<= 1) {
      int t = __shfl_up(x, off);
      if (lane >= off) x += t;
    }
    if (lane == 63) wsum[wid] = x;
    __syncthreads();
    if (wid == 0) {
      int w = (lane < 16) ? wsum[lane] : 0;
#pragma unroll
      for (int off = 1; off < 16; off <<= 1) {
        int t = __shfl_up(w, off);
        if (lane >= off) w += t;
      }
      if (lane < 16) wsum[lane] = w;
    }
    __syncthreads();
    int waveoff = (wid == 0) ? 0 : wsum[wid - 1];
    int excl = carry_s + waveoff + (x - v);
    if (i < n) { offs[i] = excl; cursor[i] = excl; }
    int total = wsum[15];
    __syncthreads();
    if (tid == 0) carry_s += total;
    __syncthreads();
  }
  if (threadIdx.x == 0) offs[n] = carry_s;
}

__global__ void scatter_kernel(const int* __restrict__ src, const int* __restrict__ dst, int E,
                               int* __restrict__ cursor, int* __restrict__ sorted_src) {
  int i = blockIdx.x * blockDim.x + threadIdx.x;
  if (i < E) {
    int p = atomicAdd(&cursor[dst[i]], 1);
    sorted_src[p] = src[i];
  }
}

// mean aggregation (fp32): one wave per dst, float2 lanes, 2-deep MLP
__global__ __launch_bounds__(256) void aggregate_mean(
    const float* __restrict__ feat, const int* __restrict__ offs,
    const int* __restrict__ sorted_src, float* __restrict__ agg, int n_dst) {
  int d = (blockIdx.x << 2) + (threadIdx.x >> 6);
  if (d >= n_dst) return;
  int lane = threadIdx.x & 63;
  int s0 = offs[d], s1 = offs[d + 1];
  float ax = 0.f, ay = 0.f;
  const float* base = feat + (lane << 1);
  int k = s0;
  for (; k + 1 < s1; k += 2) {
    int i0 = sorted_src[k];
    int i1 = sorted_src[k + 1];
    float2 v0 = *(const float2*)(base + (size_t)i0 * H);
    float2 v1 = *(const float2*)(base + (size_t)i1 * H);
    ax += v0.x + v1.x;
    ay += v0.y + v1.y;
  }
  if (k < s1) {
    int i0 = sorted_src[k];
    float2 v0 = *(const float2*)(base + (size_t)i0 * H);
    ax += v0.x;
    ay += v0.y;
  }
  float inv = 1.f / fmaxf((float)(s1 - s0), 1.f);
  *(float2*)(agg + (size_t)d * H + (lane << 1)) = make_float2(ax * inv, ay * inv);
}

// mean aggregation (fp16 source): halves the L3 gather traffic for the 1M-edge ue set
__global__ __launch_bounds__(256) void aggregate_mean_f16(
    const unsigned short* __restrict__ feat, const int* __restrict__ offs,
    const int* __restrict__ sorted_src, float* __restrict__ agg, int n_dst) {
  int d = (blockIdx.x << 2) + (threadIdx.x >> 6);
  if (d >= n_dst) return;
  int lane = threadIdx.x & 63;
  int s0 = offs[d], s1 = offs[d + 1];
  float ax = 0.f, ay = 0.f;
  const unsigned short* base = feat + (lane << 1);
  int k = s0;
  for (; k + 1 < s1; k += 2) {
    int i0 = sorted_src[k];
    int i1 = sorted_src[k + 1];
    __half2 v0 = *(const __half2*)(base + (size_t)i0 * H);
    __half2 v1 = *(const __half2*)(base + (size_t)i1 * H);
    float2 f0 = __half22float2(v0);
    float2 f1 = __half22float2(v1);
    ax += f0.x + f1.x;
    ay += f0.y + f1.y;
  }
  if (k < s1) {
    int i0 = sorted_src[k];
    float2 f0 = __half22float2(*(const __half2*)(base + (size_t)i0 * H));
    ax += f0.x;
    ay += f0.y;
  }
  float inv = 1.f / fmaxf((float)(s1 - s0), 1.f);
  *(float2*)(agg + (size_t)d * H + (lane << 1)) = make_float2(ax * inv, ay * inv);
}

// ---------------------------------------------------------------- BatchNorm stats (combined = [eh | e])
__global__ void bn_stats(const float* __restrict__ eh, const float* __restrict__ e, int M,
                         double* __restrict__ sums) {
  int t = threadIdx.x;
  double s = 0.0, s2 = 0.0;
  for (int r = blockIdx.x; r < M; r += gridDim.x) {
    float v = (t < 128) ? eh[(size_t)r * 128 + t] : e[(size_t)r * 128 + (t - 128)];
    s += v;
    s2 += (double)v * v;
  }
  atomicAdd(&sums[t], s);
  atomicAdd(&sums[256 + t], s2);
}

__global__ void bn_finalize(const double* __restrict__ sums, int M,
                            const float* __restrict__ gamma, const float* __restrict__ beta,
                            float* __restrict__ scale, float* __restrict__ shift) {
  int c = threadIdx.x;
  if (c < 256) {
    double mu = sums[c] / M;
    double var = sums[256 + c] / M - mu * mu;
    float rstd = 1.0f / sqrtf((float)var + 1e-5f);
    float g = gamma[c] * rstd;
    scale[c] = g;
    shift[c] = beta[c] - (float)mu * g;
  }
}

// ---------------------------------------------------------------- classifier KAN (256 -> 2), BN fused
// Closed-form spline: per channel only 4 indexed FMAs against a zero-padded
// LDS table (rows t = m+4, m in [-4,11]; valid m 0..7 -> t 4..11).
// Bank-check: addr = t*256 + c -> bank = c%32 -> within a wave c=lane -> conflict-free.
__global__ __launch_bounds__(256) void classifier_kan(
    const float* __restrict__ eh, const float* __restrict__ e,
    const float* __restrict__ scale, const float* __restrict__ shift,
    const float* __restrict__ base_w, const float* __restrict__ spline_w,
    float* __restrict__ out, int M) {
  __shared__ float w0p[16][256];
  __shared__ float w1p[16][256];
  __shared__ float wb0[256], wb1[256];
  __shared__ float sc[256], sh[256];
  int tid = threadIdx.x;
  for (int idx = tid; idx < 16 * 256; idx += 256) {
    int t = idx >> 8, c = idx & 255;
    int m = t - 4;
    float v0 = 0.f, v1 = 0.f;
    if (m >= 0 && m < 8) {
      v0 = spline_w[((size_t)c) * 8 + m];          // o=0
      v1 = spline_w[((size_t)(256 + c)) * 8 + m];  // o=1
    }
    w0p[t][c] = v0;
    w1p[t][c] = v1;
  }
  wb0[tid] = base_w[tid];
  wb1[tid] = base_w[256 + tid];
  sc[tid] = scale[tid];
  sh[tid] = shift[tid];
  __syncthreads();
  int wave = tid >> 6, lane = tid & 63;
  int r = blockIdx.x * 4 + wave;
  if (r >= M) return;
  float a0 = 0.f, a1 = 0.f;
#pragma unroll
  for (int mm = 0; mm < 4; ++mm) {
    int c = lane + (mm << 6);
    float xv = (c < 128) ? eh[(size_t)r * 128 + c] : e[(size_t)r * 128 + (c - 128)];
    float y = xv * sc[c] + sh[c];
    float sg = 1.f / (1.f + expf(-y));
    float si = y * sg;
    a0 += si * wb0[c];
    a1 += si * wb1[c];
    int i0;
    float P0, P1, P2, P3;
    spline_pieces(y, i0, P0, P1, P2, P3);
    i0 = i0 < -1 ? -1 : (i0 > 11 ? 11 : i0);  // clamped -> all 4 reads hit zero rows when out of range
    int t0 = i0 + 4;                          // t0 in [3,15]; t0-3 >= 0
    a0 += P0 * w0p[t0][c] + P1 * w0p[t0 - 1][c] + P2 * w0p[t0 - 2][c] + P3 * w0p[t0 - 3][c];
    a1 += P0 * w1p[t0][c] + P1 * w1p[t0 - 1][c] + P2 * w1p[t0 - 2][c] + P3 * w1p[t0 - 3][c];
  }
#pragma unroll
  for (int off = 32; off >= 1; off >>= 1) {
    a0 += __shfl_down(a0, off);
    a1 += __shfl_down(a1, off);
  }
  if (lane == 0) {
    out[(size_t)r * 2] = a0;
    out[(size_t)r * 2 + 1] = a1;
  }
}

// ---------------------------------------------------------------- launch
extern "C" void kernel_launch(void* const* d_in, const int* in_sizes, int n_in,
                              void* d_out, int out_size, void* d_ws, size_t ws_size,
                              hipStream_t stream) {
  const float* email_x   = (const float*)d_in[0];
  const float* url_x     = (const float*)d_in[1];
  const float* sender_x  = (const float*)d_in[2];
  const float* W_email   = (const float*)d_in[3];
  const float* b_email   = (const float*)d_in[4];
  const float* url_bw    = (const float*)d_in[5];
  const float* url_sw    = (const float*)d_in[6];
  const float* snd_bw    = (const float*)d_in[7];
  const float* snd_sw    = (const float*)d_in[8];
  const float* Wl_se     = (const float*)d_in[9];
  const float* bl_se     = (const float*)d_in[10];
  const float* Wr_se     = (const float*)d_in[11];
  // d_in[12..14]: eu SAGE weights — dead code in the reference (result unused)
  const float* Wl_ue     = (const float*)d_in[15];
  const float* bl_ue     = (const float*)d_in[16];
  const float* Wr_ue     = (const float*)d_in[17];
  const float* bn_gamma  = (const float*)d_in[18];
  const float* bn_beta   = (const float*)d_in[19];
  const float* cls_bw    = (const float*)d_in[20];
  const float* cls_sw    = (const float*)d_in[21];
  const int*   se_src    = (const int*)d_in[22];
  const int*   se_dst    = (const int*)d_in[23];
  // d_in[24..25]: eu edges — dead
  const int*   ue_src    = (const int*)d_in[26];
  const int*   ue_dst    = (const int*)d_in[27];

  const int N_E = in_sizes[0] / 768;
  const int N_U = in_sizes[1] / 8;
  const int N_S = in_sizes[2];
  const int E_SE = in_sizes[22];
  const int E_UE = in_sizes[26];

  char* ws = (char*)d_ws;
  size_t off = 0;
  auto alloc = [&](size_t bytes) -> void* {
    void* p = ws + off;
    off = (off + bytes + 255) & ~(size_t)255;
    return p;
  };

  float* e      = (float*)alloc((size_t)N_E * H * 4);
  // u is fp16 now; buffer reused later for fp32 eh (N_E*H*4 = 15.4MB < N_U*H*2 = 51.2MB)
  unsigned short* u = (unsigned short*)alloc((size_t)N_U * H * 2);
  float* s      = (float*)alloc((size_t)N_S * H * 4);
  float* agg_s  = (float*)alloc((size_t)N_E * H * 4);
  float* agg_u  = (float*)alloc((size_t)N_E * H * 4);
  float* wpad_u = (float*)alloc((size_t)128 * 80 * 4);
  float* wpad_s = (float*)alloc((size_t)128 * 16 * 4);
  unsigned short* wEH = (unsigned short*)alloc((size_t)24 * 8 * 64 * 8 * 2);
  unsigned short* wEL = (unsigned short*)alloc((size_t)24 * 8 * 64 * 8 * 2);
  unsigned short* wHH = (unsigned short*)alloc((size_t)12 * 8 * 64 * 8 * 2);
  unsigned short* wHL = (unsigned short*)alloc((size_t)12 * 8 * 64 * 8 * 2);
  unsigned short* wKH = (unsigned short*)alloc((size_t)3 * 8 * 64 * 8 * 2);
  unsigned short* wKL = (unsigned short*)alloc((size_t)3 * 8 * 64 * 8 * 2);
  int* cnt_se   = (int*)alloc((size_t)N_E * 4);
  int* offs_se  = (int*)alloc(((size_t)N_E + 1) * 4);
  int* cur_se   = (int*)alloc((size_t)N_E * 4);
  int* srt_se   = (int*)alloc((size_t)E_SE * 4);
  int* cnt_ue   = (int*)alloc((size_t)N_E * 4);
  int* offs_ue  = (int*)alloc(((size_t)N_E + 1) * 4);
  int* cur_ue   = (int*)alloc((size_t)N_E * 4);
  int* srt_ue   = (int*)alloc((size_t)E_UE * 4);
  double* bnsum = (double*)alloc(512 * 8);
  float* scale  = (float*)alloc(256 * 4);
  float* shift  = (float*)alloc(256 * 4);
  // u (fp16) is dead after aggregate_mean_f16; reuse its space for fp32 email_h
  float* eh = (float*)u;

  hipMemsetAsync(cnt_se, 0, (size_t)N_E * 4, stream);
  hipMemsetAsync(cnt_ue, 0, (size_t)N_E * 4, stream);
  hipMemsetAsync(bnsum, 0, 512 * 8, stream);

  // pack weights (tiny)
  build_wpad<<<(128 * 80 + 255) / 256, 256, 0, stream>>>(url_bw, url_sw, wpad_u, 8, 80);
  build_wpad<<<(128 * 16 + 255) / 256, 256, 0, stream>>>(snd_bw, snd_sw, wpad_s, 1, 16);
  pack_wfrag<<<(24 * 512 + 255) / 256, 256, 0, stream>>>(W_email, nullptr, 768, 24, wEH, wEL, 0);
  pack_wfrag<<<(4 * 512 + 255) / 256, 256, 0, stream>>>(Wl_se, nullptr, 128, 4, wHH, wHL, 0);
  pack_wfrag<<<(4 * 512 + 255) / 256, 256, 0, stream>>>(Wl_ue, nullptr, 128, 4, wHH, wHL, 4);
  pack_wfrag<<<(4 * 512 + 255) / 256, 256, 0, stream>>>(Wr_se, Wr_ue, 128, 4, wHH, wHL, 8);
  pack_wfrag_pad<<<(3 * 512 + 255) / 256, 256, 0, stream>>>(wpad_u, 80, 3, wKH, wKL);

  // node encoders
  mfma_gemm<1, 24, 1><<<(N_E + 31) / 32, 256, 0, stream>>>(
      N_E, email_x, nullptr, nullptr, wEH, wEL, b_email, nullptr, e);
  kan_mfma8<<<(N_U + 31) / 32, 256, 0, stream>>>(url_x, wKH, wKL, u, N_U);
  kan_gemm<1><<<(N_S + 63) / 64, 256, 0, stream>>>(sender_x, wpad_s, s, N_S);

  // CSR build for both email-destination edge sets
  count_kernel<<<(E_SE + 255) / 256, 256, 0, stream>>>(se_dst, E_SE, cnt_se);
  count_kernel<<<(E_UE + 255) / 256, 256, 0, stream>>>(ue_dst, E_UE, cnt_ue);
  scan_kernel<<<1, 1024, 0, stream>>>(cnt_se, N_E, offs_se, cur_se);
  scan_kernel<<<1, 1024, 0, stream>>>(cnt_ue, N_E, offs_ue, cur_ue);
  scatter_kernel<<<(E_SE + 255) / 256, 256, 0, stream>>>(se_src, se_dst, E_SE, cur_se, srt_se);
  scatter_kernel<<<(E_UE + 255) / 256, 256, 0, stream>>>(ue_src, ue_dst, E_UE, cur_ue, srt_ue);

  // mean aggregation (gather, no float atomics)
  aggregate_mean<<<(N_E + 3) / 4, 256, 0, stream>>>(s, offs_se, srt_se, agg_s, N_E);
  aggregate_mean_f16<<<(N_E + 3) / 4, 256, 0, stream>>>(u, offs_ue, srt_ue, agg_u, N_E);

  // fused email_h = lrelu(0.5*(agg_s@Wl_se^T + agg_u@Wl_ue^T + e@(Wr_se+Wr_ue)^T + bl_se + bl_ue))
  mfma_gemm<3, 4, 2><<<(N_E + 31) / 32, 256, 0, stream>>>(
      N_E, agg_s, agg_u, e, wHH, wHL, bl_se, bl_ue, eh);

  // batchnorm over combined=[eh|e], then classifier KAN (BN fused into it)
  bn_stats<<<256, 256, 0, stream>>>(eh, e, N_E, bnsum);
  bn_finalize<<<1, 256, 0, stream>>>(bnsum, N_E, bn_gamma, bn_beta, scale, shift);
  classifier_kan<<<(N_E + 3) / 4, 256, 0, stream>>>(
      eh, e, scale, shift, cls_bw, cls_sw, (float*)d_out, N_E);
}

// Round 9
// 560.399 us; speedup vs baseline: 3.9084x; 1.1711x over previous
//
#include <hip/hip_runtime.h>
#include <hip/hip_bf16.h>
#include <hip/hip_fp16.h>
#include <math.h>

#define H 128

typedef __attribute__((ext_vector_type(8))) short short8;
typedef __attribute__((ext_vector_type(4))) float f32x4;

// ---------------------------------------------------------------- bf16 split helpers
__device__ __forceinline__ unsigned short f2bf(float f) {
  union { float f; unsigned u; } c{f};
  unsigned u = c.u;
  unsigned r = (u + 0x7FFFu + ((u >> 16) & 1u)) >> 16;  // round-nearest-even
  return (unsigned short)r;
}
__device__ __forceinline__ float bf2f(unsigned short h) {
  union { unsigned u; float f; } c{(unsigned)h << 16};
  return c.f;
}
__device__ __forceinline__ void splitHL(float v, unsigned short& hi, unsigned short& lo) {
  hi = f2bf(v);
  lo = f2bf(v - bf2f(hi));
}

// ---------------------------------------------------------------- B-splines
// grid[m] = (m-3)*0.4 - 1.0, m = 0..11  (G=5, K=3 -> 8 basis functions)
__device__ __forceinline__ float gridv(int m) { return (float)(m - 3) * 0.4f - 1.0f; }

// full Cox-de Boor (used only in tiny sender KAN)
__device__ __forceinline__ void bspline8(float x, float* b) {
  float t[11];
#pragma unroll
  for (int m = 0; m < 11; ++m)
    t[m] = (x >= gridv(m) && x < gridv(m + 1)) ? 1.0f : 0.0f;
#pragma unroll
  for (int j = 1; j <= 3; ++j) {
#pragma unroll
    for (int m = 0; m + j < 11; ++m) {
      float den1 = gridv(m + j) - gridv(m);
      float den2 = gridv(m + j + 1) - gridv(m + 1);
      t[m] = (x - gridv(m)) * (1.0f / den1) * t[m] +
             (gridv(m + j + 1) - x) * (1.0f / den2) * t[m + 1];
    }
  }
#pragma unroll
  for (int m = 0; m < 8; ++m) b[m] = t[m];
}

// closed-form uniform cubic B-spline pieces (HW-verified round 8)
__device__ __forceinline__ void spline_pieces(float x, int& i0, float& P0, float& P1,
                                              float& P2, float& P3) {
  float xs = (x + 2.2f) * 2.5f;
  float fi = floorf(xs);
  float u = xs - fi;
  i0 = (int)fi;
  float u2 = u * u, u3 = u2 * u;
  P0 = u3 * (1.f / 6.f);
  P1 = (1.f + 3.f * (u + u2 - u3)) * (1.f / 6.f);
  P2 = (4.f - 6.f * u2 + 3.f * u3) * (1.f / 6.f);
  float um = 1.f - u;
  P3 = um * um * um * (1.f / 6.f);
}

// ---------------------------------------------------------------- W fragment packing (HW-verified)
__global__ void pack_wfrag(const float* __restrict__ W0, const float* __restrict__ W1,
                           int K, int NS, unsigned short* __restrict__ WH,
                           unsigned short* __restrict__ WL, int ksBase) {
  int thr = blockIdx.x * blockDim.x + threadIdx.x;
  if (thr >= NS * 512) return;
  int ks = thr >> 9;
  int rem = thr & 511;
  int cf = rem >> 6;
  int l = rem & 63;
  int o = cf * 16 + (l & 15);
  size_t obase = (((size_t)(ksBase + ks) * 8 + cf) * 64 + l) * 8;
#pragma unroll
  for (int j = 0; j < 8; ++j) {
    int k = ks * 32 + ((l >> 4) << 3) + j;
    float v = W0[(size_t)o * K + k];
    if (W1) v += W1[(size_t)o * K + k];
    unsigned short hi, lo;
    splitHL(v, hi, lo);
    WH[obase + j] = hi;
    WL[obase + j] = lo;
  }
}

__global__ void pack_wfrag_pad(const float* __restrict__ W0, int Kreal, int NS,
                               unsigned short* __restrict__ WH,
                               unsigned short* __restrict__ WL) {
  int thr = blockIdx.x * blockDim.x + threadIdx.x;
  if (thr >= NS * 512) return;
  int ks = thr >> 9;
  int rem = thr & 511;
  int cf = rem >> 6;
  int l = rem & 63;
  int o = cf * 16 + (l & 15);
  size_t obase = (((size_t)ks * 8 + cf) * 64 + l) * 8;
#pragma unroll
  for (int j = 0; j < 8; ++j) {
    int k = ks * 32 + ((l >> 4) << 3) + j;
    float v = (k < Kreal) ? W0[(size_t)o * Kreal + k] : 0.f;
    unsigned short hi, lo;
    splitHL(v, hi, lo);
    WH[obase + j] = hi;
    WL[obase + j] = lo;
  }
}

// ---------------------------------------------------------------- MFMA GEMM N=128 (HW-verified round 7)
template <int NSEG, int KSPS, int ACT>
__global__ __launch_bounds__(256) void mfma_gemm(
    int M,
    const float* __restrict__ A0, const float* __restrict__ A1, const float* __restrict__ A2,
    const unsigned short* __restrict__ WH, const unsigned short* __restrict__ WL,
    const float* __restrict__ bias0, const float* __restrict__ bias1,
    float* __restrict__ out) {
  constexpr int SEGK = KSPS * 32;
  constexpr int NST = NSEG * KSPS;
  __shared__ __align__(16) unsigned short AsH[2][32 * 40];
  __shared__ __align__(16) unsigned short AsL[2][32 * 40];

  const int tid = threadIdx.x;
  const int w = tid >> 6;
  const int l = tid & 63;
  const int rowBase = blockIdx.x * 32;

  const int lr = tid >> 3;
  const int lk = (tid & 7) << 2;

  auto loadA = [&](int kst, float4& v) {
    int seg, kk;
    if (NSEG == 1) { seg = 0; kk = kst; }
    else { seg = kst / KSPS; kk = kst - seg * KSPS; }
    const float* Ap = (seg == 0) ? A0 : ((seg == 1) ? A1 : A2);
    int rg = rowBase + lr;
    if (rg < M) v = *(const float4*)(Ap + (size_t)rg * SEGK + kk * 32 + lk);
    else v = make_float4(0.f, 0.f, 0.f, 0.f);
  };
  auto writeA = [&](int buf, const float4& v) {
    float vv[4] = {v.x, v.y, v.z, v.w};
    ushort4 hh, ll;
    unsigned short* hp = (unsigned short*)&hh;
    unsigned short* lp = (unsigned short*)&ll;
#pragma unroll
    for (int i = 0; i < 4; ++i) splitHL(vv[i], hp[i], lp[i]);
    *(ushort4*)&AsH[buf][lr * 40 + lk] = hh;
    *(ushort4*)&AsL[buf][lr * 40 + lk] = ll;
  };

  f32x4 acc[2][2] = {};

  float4 va;
  loadA(0, va);
  writeA(0, va);
  int cur = 0;

  const int fragOff = ((l >> 4) << 3);

  for (int kst = 0; kst < NST; ++kst) {
    short8 bH[2], bL[2];
#pragma unroll
    for (int c = 0; c < 2; ++c) {
      int cf = (w << 1) + c;
      size_t bi = (((size_t)kst * 8 + cf) * 64 + l) * 8;
      bH[c] = *(const short8*)(WH + bi);
      bL[c] = *(const short8*)(WL + bi);
    }
    float4 vn;
    if (kst + 1 < NST) loadA(kst + 1, vn);
    __syncthreads();
    short8 aH[2], aL[2];
#pragma unroll
    for (int r = 0; r < 2; ++r) {
      int off = ((r << 4) + (l & 15)) * 40 + fragOff;
      aH[r] = *(const short8*)&AsH[cur][off];
      aL[r] = *(const short8*)&AsL[cur][off];
    }
#pragma unroll
    for (int r = 0; r < 2; ++r)
#pragma unroll
      for (int c = 0; c < 2; ++c) {
        acc[r][c] = __builtin_amdgcn_mfma_f32_16x16x32_bf16(aH[r], bH[c], acc[r][c], 0, 0, 0);
        acc[r][c] = __builtin_amdgcn_mfma_f32_16x16x32_bf16(aH[r], bL[c], acc[r][c], 0, 0, 0);
        acc[r][c] = __builtin_amdgcn_mfma_f32_16x16x32_bf16(aL[r], bH[c], acc[r][c], 0, 0, 0);
      }
    if (kst + 1 < NST) writeA(cur ^ 1, vn);
    cur ^= 1;
  }

#pragma unroll
  for (int r = 0; r < 2; ++r)
#pragma unroll
    for (int c = 0; c < 2; ++c) {
      int col = ((w << 1) + c) * 16 + (l & 15);
      float b0 = bias0[col];
      float b1 = bias1 ? bias1[col] : 0.f;
#pragma unroll
      for (int i = 0; i < 4; ++i) {
        int row = rowBase + (r << 4) + ((l >> 4) << 2) + i;
        if (row < M) {
          float x = acc[r][c][i] + b0;
          if (ACT == 1) {
            x = tanhf(x);
          } else {
            x = (x + b1) * 0.5f;
            x = (x >= 0.f) ? x : 0.2f * x;
          }
          out[(size_t)row * H + col] = x;
        }
      }
    }
}

// ---------------------------------------------------------------- url KAN as MFMA GEMM (HW-verified round 8)
__global__ __launch_bounds__(256) void kan_mfma8(
    const float* __restrict__ x, const unsigned short* __restrict__ WH,
    const unsigned short* __restrict__ WL, unsigned short* __restrict__ out, int N) {
  constexpr int RS = 104;
  __shared__ __align__(16) unsigned short AsH[32 * RS];
  __shared__ __align__(16) unsigned short AsL[32 * RS];
  const int tid = threadIdx.x;
  const int w = tid >> 6;
  const int l = tid & 63;
  const int rowBase = blockIdx.x * 32;

  for (int idx = tid; idx < 32 * 24; idx += 256) {
    int r = idx / 24, k = 72 + idx - (idx / 24) * 24;
    AsH[r * RS + k] = 0;
    AsL[r * RS + k] = 0;
  }
  {
    int nl = tid >> 3, i = tid & 7;
    int n = rowBase + nl;
    float xv = (n < N) ? x[(size_t)n * 8 + i] : 0.f;
    float sg = 1.f / (1.f + expf(-xv));
    float si = xv * sg;
    unsigned short hi, lo;
    splitHL(si, hi, lo);
    AsH[nl * RS + i] = hi;
    AsL[nl * RS + i] = lo;
    int i0;
    float P0, P1, P2, P3;
    spline_pieces(xv, i0, P0, P1, P2, P3);
#pragma unroll
    for (int m = 0; m < 8; ++m) {
      int d = i0 - m;
      float b = (d == 0) ? P0 : (d == 1) ? P1 : (d == 2) ? P2 : (d == 3) ? P3 : 0.f;
      splitHL(b, hi, lo);
      AsH[nl * RS + 8 + i * 8 + m] = hi;
      AsL[nl * RS + 8 + i * 8 + m] = lo;
    }
  }
  __syncthreads();

  f32x4 acc[2][2] = {};
  const int fragOff = ((l >> 4) << 3);
#pragma unroll
  for (int kst = 0; kst < 3; ++kst) {
    short8 bH[2], bL[2];
#pragma unroll
    for (int c = 0; c < 2; ++c) {
      int cf = (w << 1) + c;
      size_t bi = (((size_t)kst * 8 + cf) * 64 + l) * 8;
      bH[c] = *(const short8*)(WH + bi);
      bL[c] = *(const short8*)(WL + bi);
    }
    short8 aH[2], aL[2];
#pragma unroll
    for (int r = 0; r < 2; ++r) {
      int off = ((r << 4) + (l & 15)) * RS + kst * 32 + fragOff;
      aH[r] = *(const short8*)&AsH[off];
      aL[r] = *(const short8*)&AsL[off];
    }
#pragma unroll
    for (int r = 0; r < 2; ++r)
#pragma unroll
      for (int c = 0; c < 2; ++c) {
        acc[r][c] = __builtin_amdgcn_mfma_f32_16x16x32_bf16(aH[r], bH[c], acc[r][c], 0, 0, 0);
        acc[r][c] = __builtin_amdgcn_mfma_f32_16x16x32_bf16(aH[r], bL[c], acc[r][c], 0, 0, 0);
        acc[r][c] = __builtin_amdgcn_mfma_f32_16x16x32_bf16(aL[r], bH[c], acc[r][c], 0, 0, 0);
      }
  }

#pragma unroll
  for (int r = 0; r < 2; ++r)
#pragma unroll
    for (int c = 0; c < 2; ++c) {
      int col = ((w << 1) + c) * 16 + (l & 15);
#pragma unroll
      for (int i = 0; i < 4; ++i) {
        int row = rowBase + (r << 4) + ((l >> 4) << 2) + i;
        if (row < N) {
          float v = tanhf(acc[r][c][i]);
          out[(size_t)row * H + col] = __half_as_ushort(__float2half(v));
        }
      }
    }
}

// ---------------------------------------------------------------- pack KAN weights into padded [128][KP]
__global__ void build_wpad(const float* __restrict__ base_w, const float* __restrict__ spline_w,
                           float* __restrict__ Wpad, int D, int KP) {
  int idx = blockIdx.x * blockDim.x + threadIdx.x;
  if (idx >= 128 * KP) return;
  int o = idx / KP, k = idx - o * KP;
  float v = 0.f;
  if (k < D) v = base_w[o * D + k];
  else if (k < 9 * D) v = spline_w[o * D * 8 + (k - D)];
  Wpad[idx] = v;
}

// ---------------------------------------------------------------- small fused KAN (sender, D=1)
template <int D>
__global__ __launch_bounds__(256) void kan_gemm(
    const float* __restrict__ x, const float* __restrict__ Wpad,
    float* __restrict__ out, int N) {
  constexpr int KP = (9 * D + 15) & ~15;
  __shared__ float As[KP][68];
  __shared__ float Bs[16][132];
  const int tid = threadIdx.x;
  const int rowBase = blockIdx.x * 64;

  for (int idx = tid; idx < 64 * D; idx += 256) {
    int nl = idx / D, i = idx - nl * D;
    int n = rowBase + nl;
    float xv = (n < N) ? x[(size_t)n * D + i] : 0.f;
    float sg = 1.f / (1.f + expf(-xv));
    float b[8];
    bspline8(xv, b);
    As[i][nl] = xv * sg;
#pragma unroll
    for (int m = 0; m < 8; ++m) As[D + i * 8 + m][nl] = b[m];
  }
  for (int idx = tid; idx < (KP - 9 * D) * 64; idx += 256) {
    int r = idx >> 6, c = idx & 63;
    As[9 * D + r][c] = 0.f;
  }

  const int rb = (tid >> 5) << 3;
  const int cb = (tid & 31) << 2;
  const int bo = tid >> 1;
  const int bk = (tid & 1) << 3;
  float acc[8][4] = {};

  for (int kc = 0; kc < KP / 16; ++kc) {
    int koff = kc << 4;
    float4 bv0 = *(const float4*)(Wpad + (size_t)bo * KP + koff + bk);
    float4 bv1 = *(const float4*)(Wpad + (size_t)bo * KP + koff + bk + 4);
    __syncthreads();
    Bs[bk + 0][bo] = bv0.x; Bs[bk + 1][bo] = bv0.y; Bs[bk + 2][bo] = bv0.z; Bs[bk + 3][bo] = bv0.w;
    Bs[bk + 4][bo] = bv1.x; Bs[bk + 5][bo] = bv1.y; Bs[bk + 6][bo] = bv1.z; Bs[bk + 7][bo] = bv1.w;
    __syncthreads();
#pragma unroll
    for (int k = 0; k < 16; ++k) {
      float4 a0 = *(const float4*)&As[koff + k][rb];
      float4 a1 = *(const float4*)&As[koff + k][rb + 4];
      float4 b = *(const float4*)&Bs[k][cb];
      float a[8] = {a0.x, a0.y, a0.z, a0.w, a1.x, a1.y, a1.z, a1.w};
      float bb[4] = {b.x, b.y, b.z, b.w};
#pragma unroll
      for (int r = 0; r < 8; ++r)
#pragma unroll
        for (int c = 0; c < 4; ++c) acc[r][c] += a[r] * bb[c];
    }
  }

#pragma unroll
  for (int r = 0; r < 8; ++r) {
    int n = rowBase + rb + r;
    if (n < N) {
      float v[4] = {tanhf(acc[r][0]), tanhf(acc[r][1]), tanhf(acc[r][2]), tanhf(acc[r][3])};
      *(float4*)(out + (size_t)n * H + cb) = *(float4*)v;
    }
  }
}

// ---------------------------------------------------------------- CSR build
__global__ void count_kernel(const int* __restrict__ dst, int E, int* __restrict__ cnt) {
  int i = blockIdx.x * blockDim.x + threadIdx.x;
  if (i < E) atomicAdd(&cnt[dst[i]], 1);
}

// 3-phase multi-block scan (replaces whole-GPU-idle single-block scan)
// p1: per-block (1024) local exclusive scan, block total -> bsum
__global__ __launch_bounds__(1024) void scan_p1(
    const int* __restrict__ cnt, int n, int* __restrict__ offs, int* __restrict__ bsum) {
  __shared__ int wsum[16];
  const int tid = threadIdx.x;
  const int lane = tid & 63;
  const int wid = tid >> 6;
  int i = blockIdx.x * 1024 + tid;
  int v = (i < n) ? cnt[i] : 0;
  int x = v;
#pragma unroll
  for (int off = 1; off < 64; off <<= 1) {
    int t = __shfl_up(x, off);
    if (lane >= off) x += t;
  }
  if (lane == 63) wsum[wid] = x;
  __syncthreads();
  if (wid == 0) {
    int w = (lane < 16) ? wsum[lane] : 0;
#pragma unroll
    for (int off = 1; off < 16; off <<= 1) {
      int t = __shfl_up(w, off);
      if (lane >= off) w += t;
    }
    if (lane < 16) wsum[lane] = w;
  }
  __syncthreads();
  int excl = ((wid == 0) ? 0 : wsum[wid - 1]) + x - v;
  if (i < n) offs[i] = excl;
  if (tid == 0) bsum[blockIdx.x] = wsum[15];
}

// p2: single-wave exclusive scan of block totals (nb <= 64); bsum[nb] = grand total
__global__ void scan_p2(int* __restrict__ bsum, int nb) {
  int tid = threadIdx.x;
  if (tid < 64) {
    int v = (tid < nb) ? bsum[tid] : 0;
    int x = v;
#pragma unroll
    for (int off = 1; off < 64; off <<= 1) {
      int t = __shfl_up(x, off);
      if (tid >= off) x += t;
    }
    if (tid < nb) bsum[tid] = x - v;
    if (tid == 63) bsum[nb] = x;
  }
}

// p3: add block prefix, produce cursor copy and offs[n]
__global__ void scan_p3(int* __restrict__ offs, int* __restrict__ cursor,
                        const int* __restrict__ bsum, int n) {
  int i = blockIdx.x * blockDim.x + threadIdx.x;
  if (i < n) {
    int o = offs[i] + bsum[i >> 10];
    offs[i] = o;
    cursor[i] = o;
  }
  if (i == 0) offs[n] = bsum[(n + 1023) >> 10];
}

__global__ void scatter_kernel(const int* __restrict__ src, const int* __restrict__ dst, int E,
                               int* __restrict__ cursor, int* __restrict__ sorted_src) {
  int i = blockIdx.x * blockDim.x + threadIdx.x;
  if (i < E) {
    int p = atomicAdd(&cursor[dst[i]], 1);
    sorted_src[p] = src[i];
  }
}

// mean aggregation (fp32): one wave per dst, float2 lanes, 4-deep MLP
__global__ __launch_bounds__(256) void aggregate_mean(
    const float* __restrict__ feat, const int* __restrict__ offs,
    const int* __restrict__ sorted_src, float* __restrict__ agg, int n_dst) {
  int d = (blockIdx.x << 2) + (threadIdx.x >> 6);
  if (d >= n_dst) return;
  int lane = threadIdx.x & 63;
  int s0 = offs[d], s1 = offs[d + 1];
  float ax = 0.f, ay = 0.f;
  const float* base = feat + (lane << 1);
  int k = s0;
  for (; k + 3 < s1; k += 4) {
    int i0 = sorted_src[k], i1 = sorted_src[k + 1];
    int i2 = sorted_src[k + 2], i3 = sorted_src[k + 3];
    float2 v0 = *(const float2*)(base + (size_t)i0 * H);
    float2 v1 = *(const float2*)(base + (size_t)i1 * H);
    float2 v2 = *(const float2*)(base + (size_t)i2 * H);
    float2 v3 = *(const float2*)(base + (size_t)i3 * H);
    ax += (v0.x + v1.x) + (v2.x + v3.x);
    ay += (v0.y + v1.y) + (v2.y + v3.y);
  }
  for (; k < s1; ++k) {
    int i0 = sorted_src[k];
    float2 v0 = *(const float2*)(base + (size_t)i0 * H);
    ax += v0.x;
    ay += v0.y;
  }
  float inv = 1.f / fmaxf((float)(s1 - s0), 1.f);
  *(float2*)(agg + (size_t)d * H + (lane << 1)) = make_float2(ax * inv, ay * inv);
}

// mean aggregation (fp16 source), 4-deep MLP
__global__ __launch_bounds__(256) void aggregate_mean_f16(
    const unsigned short* __restrict__ feat, const int* __restrict__ offs,
    const int* __restrict__ sorted_src, float* __restrict__ agg, int n_dst) {
  int d = (blockIdx.x << 2) + (threadIdx.x >> 6);
  if (d >= n_dst) return;
  int lane = threadIdx.x & 63;
  int s0 = offs[d], s1 = offs[d + 1];
  float ax = 0.f, ay = 0.f;
  const unsigned short* base = feat + (lane << 1);
  int k = s0;
  for (; k + 3 < s1; k += 4) {
    int i0 = sorted_src[k], i1 = sorted_src[k + 1];
    int i2 = sorted_src[k + 2], i3 = sorted_src[k + 3];
    float2 f0 = __half22float2(*(const __half2*)(base + (size_t)i0 * H));
    float2 f1 = __half22float2(*(const __half2*)(base + (size_t)i1 * H));
    float2 f2 = __half22float2(*(const __half2*)(base + (size_t)i2 * H));
    float2 f3 = __half22float2(*(const __half2*)(base + (size_t)i3 * H));
    ax += (f0.x + f1.x) + (f2.x + f3.x);
    ay += (f0.y + f1.y) + (f2.y + f3.y);
  }
  for (; k < s1; ++k) {
    int i0 = sorted_src[k];
    float2 f0 = __half22float2(*(const __half2*)(base + (size_t)i0 * H));
    ax += f0.x;
    ay += f0.y;
  }
  float inv = 1.f / fmaxf((float)(s1 - s0), 1.f);
  *(float2*)(agg + (size_t)d * H + (lane << 1)) = make_float2(ax * inv, ay * inv);
}

// ---------------------------------------------------------------- BatchNorm stats (combined = [eh | e])
__global__ void bn_stats(const float* __restrict__ eh, const float* __restrict__ e, int M,
                         double* __restrict__ sums) {
  int t = threadIdx.x;
  double s = 0.0, s2 = 0.0;
  for (int r = blockIdx.x; r < M; r += gridDim.x) {
    float v = (t < 128) ? eh[(size_t)r * 128 + t] : e[(size_t)r * 128 + (t - 128)];
    s += v;
    s2 += (double)v * v;
  }
  atomicAdd(&sums[t], s);
  atomicAdd(&sums[256 + t], s2);
}

__global__ void bn_finalize(const double* __restrict__ sums, int M,
                            const float* __restrict__ gamma, const float* __restrict__ beta,
                            float* __restrict__ scale, float* __restrict__ shift) {
  int c = threadIdx.x;
  if (c < 256) {
    double mu = sums[c] / M;
    double var = sums[256 + c] / M - mu * mu;
    float rstd = 1.0f / sqrtf((float)var + 1e-5f);
    float g = gamma[c] * rstd;
    scale[c] = g;
    shift[c] = beta[c] - (float)mu * g;
  }
}

// ---------------------------------------------------------------- classifier KAN (256 -> 2), BN fused
// Persistent blocks: LDS table filled ONCE per block, then grid-stride over rows.
// (Round-8 version paid the 32KB fill for every 4 rows -> prologue-bound at 70us.)
__global__ __launch_bounds__(256) void classifier_kan(
    const float* __restrict__ eh, const float* __restrict__ e,
    const float* __restrict__ scale, const float* __restrict__ shift,
    const float* __restrict__ base_w, const float* __restrict__ spline_w,
    float* __restrict__ out, int M) {
  __shared__ float w0p[16][256];
  __shared__ float w1p[16][256];
  __shared__ float wb0[256], wb1[256];
  __shared__ float sc[256], sh[256];
  int tid = threadIdx.x;
  for (int idx = tid; idx < 16 * 256; idx += 256) {
    int t = idx >> 8, c = idx & 255;
    int m = t - 4;
    float v0 = 0.f, v1 = 0.f;
    if (m >= 0 && m < 8) {
      v0 = spline_w[((size_t)c) * 8 + m];
      v1 = spline_w[((size_t)(256 + c)) * 8 + m];
    }
    w0p[t][c] = v0;
    w1p[t][c] = v1;
  }
  wb0[tid] = base_w[tid];
  wb1[tid] = base_w[256 + tid];
  sc[tid] = scale[tid];
  sh[tid] = shift[tid];
  __syncthreads();
  int wave = tid >> 6, lane = tid & 63;
  for (int r = blockIdx.x * 4 + wave; r < M; r += gridDim.x * 4) {
    float a0 = 0.f, a1 = 0.f;
#pragma unroll
    for (int mm = 0; mm < 4; ++mm) {
      int c = lane + (mm << 6);
      float xv = (c < 128) ? eh[(size_t)r * 128 + c] : e[(size_t)r * 128 + (c - 128)];
      float y = xv * sc[c] + sh[c];
      float sg = 1.f / (1.f + expf(-y));
      float si = y * sg;
      a0 += si * wb0[c];
      a1 += si * wb1[c];
      int i0;
      float P0, P1, P2, P3;
      spline_pieces(y, i0, P0, P1, P2, P3);
      i0 = i0 < -1 ? -1 : (i0 > 11 ? 11 : i0);
      int t0 = i0 + 4;
      a0 += P0 * w0p[t0][c] + P1 * w0p[t0 - 1][c] + P2 * w0p[t0 - 2][c] + P3 * w0p[t0 - 3][c];
      a1 += P0 * w1p[t0][c] + P1 * w1p[t0 - 1][c] + P2 * w1p[t0 - 2][c] + P3 * w1p[t0 - 3][c];
    }
#pragma unroll
    for (int off = 32; off >= 1; off >>= 1) {
      a0 += __shfl_down(a0, off);
      a1 += __shfl_down(a1, off);
    }
    if (lane == 0) {
      out[(size_t)r * 2] = a0;
      out[(size_t)r * 2 + 1] = a1;
    }
  }
}

// ---------------------------------------------------------------- launch
extern "C" void kernel_launch(void* const* d_in, const int* in_sizes, int n_in,
                              void* d_out, int out_size, void* d_ws, size_t ws_size,
                              hipStream_t stream) {
  const float* email_x   = (const float*)d_in[0];
  const float* url_x     = (const float*)d_in[1];
  const float* sender_x  = (const float*)d_in[2];
  const float* W_email   = (const float*)d_in[3];
  const float* b_email   = (const float*)d_in[4];
  const float* url_bw    = (const float*)d_in[5];
  const float* url_sw    = (const float*)d_in[6];
  const float* snd_bw    = (const float*)d_in[7];
  const float* snd_sw    = (const float*)d_in[8];
  const float* Wl_se     = (const float*)d_in[9];
  const float* bl_se     = (const float*)d_in[10];
  const float* Wr_se     = (const float*)d_in[11];
  // d_in[12..14]: eu SAGE weights — dead code in the reference (result unused)
  const float* Wl_ue     = (const float*)d_in[15];
  const float* bl_ue     = (const float*)d_in[16];
  const float* Wr_ue     = (const float*)d_in[17];
  const float* bn_gamma  = (const float*)d_in[18];
  const float* bn_beta   = (const float*)d_in[19];
  const float* cls_bw    = (const float*)d_in[20];
  const float* cls_sw    = (const float*)d_in[21];
  const int*   se_src    = (const int*)d_in[22];
  const int*   se_dst    = (const int*)d_in[23];
  // d_in[24..25]: eu edges — dead
  const int*   ue_src    = (const int*)d_in[26];
  const int*   ue_dst    = (const int*)d_in[27];

  const int N_E = in_sizes[0] / 768;
  const int N_U = in_sizes[1] / 8;
  const int N_S = in_sizes[2];
  const int E_SE = in_sizes[22];
  const int E_UE = in_sizes[26];

  char* ws = (char*)d_ws;
  size_t off = 0;
  auto alloc = [&](size_t bytes) -> void* {
    void* p = ws + off;
    off = (off + bytes + 255) & ~(size_t)255;
    return p;
  };

  float* e      = (float*)alloc((size_t)N_E * H * 4);
  // u is fp16; buffer reused later for fp32 eh (N_E*H*4 = 15.4MB < N_U*H*2 = 51.2MB)
  unsigned short* u = (unsigned short*)alloc((size_t)N_U * H * 2);
  float* s      = (float*)alloc((size_t)N_S * H * 4);
  float* agg_s  = (float*)alloc((size_t)N_E * H * 4);
  float* agg_u  = (float*)alloc((size_t)N_E * H * 4);
  float* wpad_u = (float*)alloc((size_t)128 * 80 * 4);
  float* wpad_s = (float*)alloc((size_t)128 * 16 * 4);
  unsigned short* wEH = (unsigned short*)alloc((size_t)24 * 8 * 64 * 8 * 2);
  unsigned short* wEL = (unsigned short*)alloc((size_t)24 * 8 * 64 * 8 * 2);
  unsigned short* wHH = (unsigned short*)alloc((size_t)12 * 8 * 64 * 8 * 2);
  unsigned short* wHL = (unsigned short*)alloc((size_t)12 * 8 * 64 * 8 * 2);
  unsigned short* wKH = (unsigned short*)alloc((size_t)3 * 8 * 64 * 8 * 2);
  unsigned short* wKL = (unsigned short*)alloc((size_t)3 * 8 * 64 * 8 * 2);
  int* cnt_se   = (int*)alloc((size_t)N_E * 4);
  int* offs_se  = (int*)alloc(((size_t)N_E + 1) * 4);
  int* cur_se   = (int*)alloc((size_t)N_E * 4);
  int* srt_se   = (int*)alloc((size_t)E_SE * 4);
  int* cnt_ue   = (int*)alloc((size_t)N_E * 4);
  int* offs_ue  = (int*)alloc(((size_t)N_E + 1) * 4);
  int* cur_ue   = (int*)alloc((size_t)N_E * 4);
  int* srt_ue   = (int*)alloc((size_t)E_UE * 4);
  int* bsum_se  = (int*)alloc(64 * 4);
  int* bsum_ue  = (int*)alloc(64 * 4);
  double* bnsum = (double*)alloc(512 * 8);
  float* scale  = (float*)alloc(256 * 4);
  float* shift  = (float*)alloc(256 * 4);
  // u (fp16) is dead after aggregate_mean_f16; reuse its space for fp32 email_h
  float* eh = (float*)u;

  hipMemsetAsync(cnt_se, 0, (size_t)N_E * 4, stream);
  hipMemsetAsync(cnt_ue, 0, (size_t)N_E * 4, stream);
  hipMemsetAsync(bnsum, 0, 512 * 8, stream);

  // pack weights (tiny)
  build_wpad<<<(128 * 80 + 255) / 256, 256, 0, stream>>>(url_bw, url_sw, wpad_u, 8, 80);
  build_wpad<<<(128 * 16 + 255) / 256, 256, 0, stream>>>(snd_bw, snd_sw, wpad_s, 1, 16);
  pack_wfrag<<<(24 * 512 + 255) / 256, 256, 0, stream>>>(W_email, nullptr, 768, 24, wEH, wEL, 0);
  pack_wfrag<<<(4 * 512 + 255) / 256, 256, 0, stream>>>(Wl_se, nullptr, 128, 4, wHH, wHL, 0);
  pack_wfrag<<<(4 * 512 + 255) / 256, 256, 0, stream>>>(Wl_ue, nullptr, 128, 4, wHH, wHL, 4);
  pack_wfrag<<<(4 * 512 + 255) / 256, 256, 0, stream>>>(Wr_se, Wr_ue, 128, 4, wHH, wHL, 8);
  pack_wfrag_pad<<<(3 * 512 + 255) / 256, 256, 0, stream>>>(wpad_u, 80, 3, wKH, wKL);

  // node encoders
  mfma_gemm<1, 24, 1><<<(N_E + 31) / 32, 256, 0, stream>>>(
      N_E, email_x, nullptr, nullptr, wEH, wEL, b_email, nullptr, e);
  kan_mfma8<<<(N_U + 31) / 32, 256, 0, stream>>>(url_x, wKH, wKL, u, N_U);
  kan_gemm<1><<<(N_S + 63) / 64, 256, 0, stream>>>(sender_x, wpad_s, s, N_S);

  // CSR build for both email-destination edge sets (3-phase multi-block scans)
  const int nb = (N_E + 1023) / 1024;
  count_kernel<<<(E_SE + 255) / 256, 256, 0, stream>>>(se_dst, E_SE, cnt_se);
  count_kernel<<<(E_UE + 255) / 256, 256, 0, stream>>>(ue_dst, E_UE, cnt_ue);
  scan_p1<<<nb, 1024, 0, stream>>>(cnt_se, N_E, offs_se, bsum_se);
  scan_p1<<<nb, 1024, 0, stream>>>(cnt_ue, N_E, offs_ue, bsum_ue);
  scan_p2<<<1, 64, 0, stream>>>(bsum_se, nb);
  scan_p2<<<1, 64, 0, stream>>>(bsum_ue, nb);
  scan_p3<<<(N_E + 255) / 256, 256, 0, stream>>>(offs_se, cur_se, bsum_se, N_E);
  scan_p3<<<(N_E + 255) / 256, 256, 0, stream>>>(offs_ue, cur_ue, bsum_ue, N_E);
  scatter_kernel<<<(E_SE + 255) / 256, 256, 0, stream>>>(se_src, se_dst, E_SE, cur_se, srt_se);
  scatter_kernel<<<(E_UE + 255) / 256, 256, 0, stream>>>(ue_src, ue_dst, E_UE, cur_ue, srt_ue);

  // mean aggregation (gather, no float atomics)
  aggregate_mean<<<(N_E + 3) / 4, 256, 0, stream>>>(s, offs_se, srt_se, agg_s, N_E);
  aggregate_mean_f16<<<(N_E + 3) / 4, 256, 0, stream>>>(u, offs_ue, srt_ue, agg_u, N_E);

  // fused email_h = lrelu(0.5*(agg_s@Wl_se^T + agg_u@Wl_ue^T + e@(Wr_se+Wr_ue)^T + bl_se + bl_ue))
  mfma_gemm<3, 4, 2><<<(N_E + 31) / 32, 256, 0, stream>>>(
      N_E, agg_s, agg_u, e, wHH, wHL, bl_se, bl_ue, eh);

  // batchnorm over combined=[eh|e], then classifier KAN (BN fused, persistent blocks)
  bn_stats<<<256, 256, 0, stream>>>(eh, e, N_E, bnsum);
  bn_finalize<<<1, 256, 0, stream>>>(bnsum, N_E, bn_gamma, bn_beta, scale, shift);
  classifier_kan<<<512, 256, 0, stream>>>(
      eh, e, scale, shift, cls_bw, cls_sw, (float*)d_out, N_E);
}

// Round 10
// 520.284 us; speedup vs baseline: 4.2097x; 1.0771x over previous
//
#include <hip/hip_runtime.h>
#include <hip/hip_bf16.h>
#include <hip/hip_fp16.h>
#include <math.h>

#define H 128

typedef __attribute__((ext_vector_type(8))) short short8;
typedef __attribute__((ext_vector_type(4))) float f32x4;

// ---------------------------------------------------------------- bf16 split helpers
__device__ __forceinline__ unsigned short f2bf(float f) {
  union { float f; unsigned u; } c{f};
  unsigned u = c.u;
  unsigned r = (u + 0x7FFFu + ((u >> 16) & 1u)) >> 16;  // round-nearest-even
  return (unsigned short)r;
}
__device__ __forceinline__ float bf2f(unsigned short h) {
  union { unsigned u; float f; } c{(unsigned)h << 16};
  return c.f;
}
__device__ __forceinline__ void splitHL(float v, unsigned short& hi, unsigned short& lo) {
  hi = f2bf(v);
  lo = f2bf(v - bf2f(hi));
}

// ---------------------------------------------------------------- B-splines
__device__ __forceinline__ float gridv(int m) { return (float)(m - 3) * 0.4f - 1.0f; }

// full Cox-de Boor (used only in tiny sender KAN)
__device__ __forceinline__ void bspline8(float x, float* b) {
  float t[11];
#pragma unroll
  for (int m = 0; m < 11; ++m)
    t[m] = (x >= gridv(m) && x < gridv(m + 1)) ? 1.0f : 0.0f;
#pragma unroll
  for (int j = 1; j <= 3; ++j) {
#pragma unroll
    for (int m = 0; m + j < 11; ++m) {
      float den1 = gridv(m + j) - gridv(m);
      float den2 = gridv(m + j + 1) - gridv(m + 1);
      t[m] = (x - gridv(m)) * (1.0f / den1) * t[m] +
             (gridv(m + j + 1) - x) * (1.0f / den2) * t[m + 1];
    }
  }
#pragma unroll
  for (int m = 0; m < 8; ++m) b[m] = t[m];
}

// closed-form uniform cubic B-spline pieces (HW-verified round 8)
__device__ __forceinline__ void spline_pieces(float x, int& i0, float& P0, float& P1,
                                              float& P2, float& P3) {
  float xs = (x + 2.2f) * 2.5f;
  float fi = floorf(xs);
  float u = xs - fi;
  i0 = (int)fi;
  float u2 = u * u, u3 = u2 * u;
  P0 = u3 * (1.f / 6.f);
  P1 = (1.f + 3.f * (u + u2 - u3)) * (1.f / 6.f);
  P2 = (4.f - 6.f * u2 + 3.f * u3) * (1.f / 6.f);
  float um = 1.f - u;
  P3 = um * um * um * (1.f / 6.f);
}

// ---------------------------------------------------------------- W fragment packing (HW-verified)
// B-frag: lane l -> col l&15, k = (l>>4)*8 + j.
__global__ void pack_wfrag(const float* __restrict__ W0, const float* __restrict__ W1,
                           int K, int NS, unsigned short* __restrict__ WH,
                           unsigned short* __restrict__ WL, int ksBase) {
  int thr = blockIdx.x * blockDim.x + threadIdx.x;
  if (thr >= NS * 512) return;
  int ks = thr >> 9;
  int rem = thr & 511;
  int cf = rem >> 6;
  int l = rem & 63;
  int o = cf * 16 + (l & 15);
  size_t obase = (((size_t)(ksBase + ks) * 8 + cf) * 64 + l) * 8;
#pragma unroll
  for (int j = 0; j < 8; ++j) {
    int k = ks * 32 + ((l >> 4) << 3) + j;
    float v = W0[(size_t)o * K + k];
    if (W1) v += W1[(size_t)o * K + k];
    unsigned short hi, lo;
    splitHL(v, hi, lo);
    WH[obase + j] = hi;
    WL[obase + j] = lo;
  }
}

// merged packing for the email_h GEMM weights: 12 k-steps
// ks 0-3: Wl_se, ks 4-7: Wl_ue, ks 8-11: Wr_se+Wr_ue (all K=128)
__global__ void pack_wfrag_h(const float* __restrict__ Wl_se, const float* __restrict__ Wl_ue,
                             const float* __restrict__ Wr_se, const float* __restrict__ Wr_ue,
                             unsigned short* __restrict__ WH, unsigned short* __restrict__ WL) {
  int thr = blockIdx.x * blockDim.x + threadIdx.x;
  if (thr >= 12 * 512) return;
  int ks = thr >> 9;
  int rem = thr & 511;
  int cf = rem >> 6;
  int l = rem & 63;
  int o = cf * 16 + (l & 15);
  const float* W0;
  const float* W1 = nullptr;
  int kk = ks;
  if (ks < 4) { W0 = Wl_se; }
  else if (ks < 8) { W0 = Wl_ue; kk = ks - 4; }
  else { W0 = Wr_se; W1 = Wr_ue; kk = ks - 8; }
  size_t obase = (((size_t)ks * 8 + cf) * 64 + l) * 8;
#pragma unroll
  for (int j = 0; j < 8; ++j) {
    int k = kk * 32 + ((l >> 4) << 3) + j;
    float v = W0[(size_t)o * 128 + k];
    if (W1) v += W1[(size_t)o * 128 + k];
    unsigned short hi, lo;
    splitHL(v, hi, lo);
    WH[obase + j] = hi;
    WL[obase + j] = lo;
  }
}

// direct url-KAN weight packing (replaces build_wpad(url)+pack_wfrag_pad):
// feature k: k<8 -> base_w[o][k]; 8<=k<72 -> spline_w[o][(k-8)/8][(k-8)%8]; else 0
__global__ void pack_kan_frag(const float* __restrict__ base_w, const float* __restrict__ spline_w,
                              unsigned short* __restrict__ WH, unsigned short* __restrict__ WL) {
  int thr = blockIdx.x * blockDim.x + threadIdx.x;
  if (thr >= 3 * 512) return;
  int ks = thr >> 9;
  int rem = thr & 511;
  int cf = rem >> 6;
  int l = rem & 63;
  int o = cf * 16 + (l & 15);
  size_t obase = (((size_t)ks * 8 + cf) * 64 + l) * 8;
#pragma unroll
  for (int j = 0; j < 8; ++j) {
    int k = ks * 32 + ((l >> 4) << 3) + j;
    float v = 0.f;
    if (k < 8) v = base_w[o * 8 + k];
    else if (k < 72) v = spline_w[(size_t)o * 64 + (k - 8)];
    unsigned short hi, lo;
    splitHL(v, hi, lo);
    WH[obase + j] = hi;
    WL[obase + j] = lo;
  }
}

// ---------------------------------------------------------------- MFMA GEMM N=128 (HW-verified round 7)
template <int NSEG, int KSPS, int ACT>
__global__ __launch_bounds__(256) void mfma_gemm(
    int M,
    const float* __restrict__ A0, const float* __restrict__ A1, const float* __restrict__ A2,
    const unsigned short* __restrict__ WH, const unsigned short* __restrict__ WL,
    const float* __restrict__ bias0, const float* __restrict__ bias1,
    float* __restrict__ out) {
  constexpr int SEGK = KSPS * 32;
  constexpr int NST = NSEG * KSPS;
  __shared__ __align__(16) unsigned short AsH[2][32 * 40];
  __shared__ __align__(16) unsigned short AsL[2][32 * 40];

  const int tid = threadIdx.x;
  const int w = tid >> 6;
  const int l = tid & 63;
  const int rowBase = blockIdx.x * 32;

  const int lr = tid >> 3;
  const int lk = (tid & 7) << 2;

  auto loadA = [&](int kst, float4& v) {
    int seg, kk;
    if (NSEG == 1) { seg = 0; kk = kst; }
    else { seg = kst / KSPS; kk = kst - seg * KSPS; }
    const float* Ap = (seg == 0) ? A0 : ((seg == 1) ? A1 : A2);
    int rg = rowBase + lr;
    if (rg < M) v = *(const float4*)(Ap + (size_t)rg * SEGK + kk * 32 + lk);
    else v = make_float4(0.f, 0.f, 0.f, 0.f);
  };
  auto writeA = [&](int buf, const float4& v) {
    float vv[4] = {v.x, v.y, v.z, v.w};
    ushort4 hh, ll;
    unsigned short* hp = (unsigned short*)&hh;
    unsigned short* lp = (unsigned short*)&ll;
#pragma unroll
    for (int i = 0; i < 4; ++i) splitHL(vv[i], hp[i], lp[i]);
    *(ushort4*)&AsH[buf][lr * 40 + lk] = hh;
    *(ushort4*)&AsL[buf][lr * 40 + lk] = ll;
  };

  f32x4 acc[2][2] = {};

  float4 va;
  loadA(0, va);
  writeA(0, va);
  int cur = 0;

  const int fragOff = ((l >> 4) << 3);

  for (int kst = 0; kst < NST; ++kst) {
    short8 bH[2], bL[2];
#pragma unroll
    for (int c = 0; c < 2; ++c) {
      int cf = (w << 1) + c;
      size_t bi = (((size_t)kst * 8 + cf) * 64 + l) * 8;
      bH[c] = *(const short8*)(WH + bi);
      bL[c] = *(const short8*)(WL + bi);
    }
    float4 vn;
    if (kst + 1 < NST) loadA(kst + 1, vn);
    __syncthreads();
    short8 aH[2], aL[2];
#pragma unroll
    for (int r = 0; r < 2; ++r) {
      int off = ((r << 4) + (l & 15)) * 40 + fragOff;
      aH[r] = *(const short8*)&AsH[cur][off];
      aL[r] = *(const short8*)&AsL[cur][off];
    }
#pragma unroll
    for (int r = 0; r < 2; ++r)
#pragma unroll
      for (int c = 0; c < 2; ++c) {
        acc[r][c] = __builtin_amdgcn_mfma_f32_16x16x32_bf16(aH[r], bH[c], acc[r][c], 0, 0, 0);
        acc[r][c] = __builtin_amdgcn_mfma_f32_16x16x32_bf16(aH[r], bL[c], acc[r][c], 0, 0, 0);
        acc[r][c] = __builtin_amdgcn_mfma_f32_16x16x32_bf16(aL[r], bH[c], acc[r][c], 0, 0, 0);
      }
    if (kst + 1 < NST) writeA(cur ^ 1, vn);
    cur ^= 1;
  }

#pragma unroll
  for (int r = 0; r < 2; ++r)
#pragma unroll
    for (int c = 0; c < 2; ++c) {
      int col = ((w << 1) + c) * 16 + (l & 15);
      float b0 = bias0[col];
      float b1 = bias1 ? bias1[col] : 0.f;
#pragma unroll
      for (int i = 0; i < 4; ++i) {
        int row = rowBase + (r << 4) + ((l >> 4) << 2) + i;
        if (row < M) {
          float x = acc[r][c][i] + b0;
          if (ACT == 1) {
            x = tanhf(x);
          } else {
            x = (x + b1) * 0.5f;
            x = (x >= 0.f) ? x : 0.2f * x;
          }
          out[(size_t)row * H + col] = x;
        }
      }
    }
}

// ---------------------------------------------------------------- url KAN as MFMA GEMM (HW-verified round 8)
__global__ __launch_bounds__(256) void kan_mfma8(
    const float* __restrict__ x, const unsigned short* __restrict__ WH,
    const unsigned short* __restrict__ WL, unsigned short* __restrict__ out, int N) {
  constexpr int RS = 104;
  __shared__ __align__(16) unsigned short AsH[32 * RS];
  __shared__ __align__(16) unsigned short AsL[32 * RS];
  const int tid = threadIdx.x;
  const int w = tid >> 6;
  const int l = tid & 63;
  const int rowBase = blockIdx.x * 32;

  for (int idx = tid; idx < 32 * 24; idx += 256) {
    int r = idx / 24, k = 72 + idx - (idx / 24) * 24;
    AsH[r * RS + k] = 0;
    AsL[r * RS + k] = 0;
  }
  {
    int nl = tid >> 3, i = tid & 7;
    int n = rowBase + nl;
    float xv = (n < N) ? x[(size_t)n * 8 + i] : 0.f;
    float sg = 1.f / (1.f + expf(-xv));
    float si = xv * sg;
    unsigned short hi, lo;
    splitHL(si, hi, lo);
    AsH[nl * RS + i] = hi;
    AsL[nl * RS + i] = lo;
    int i0;
    float P0, P1, P2, P3;
    spline_pieces(xv, i0, P0, P1, P2, P3);
#pragma unroll
    for (int m = 0; m < 8; ++m) {
      int d = i0 - m;
      float b = (d == 0) ? P0 : (d == 1) ? P1 : (d == 2) ? P2 : (d == 3) ? P3 : 0.f;
      splitHL(b, hi, lo);
      AsH[nl * RS + 8 + i * 8 + m] = hi;
      AsL[nl * RS + 8 + i * 8 + m] = lo;
    }
  }
  __syncthreads();

  f32x4 acc[2][2] = {};
  const int fragOff = ((l >> 4) << 3);
#pragma unroll
  for (int kst = 0; kst < 3; ++kst) {
    short8 bH[2], bL[2];
#pragma unroll
    for (int c = 0; c < 2; ++c) {
      int cf = (w << 1) + c;
      size_t bi = (((size_t)kst * 8 + cf) * 64 + l) * 8;
      bH[c] = *(const short8*)(WH + bi);
      bL[c] = *(const short8*)(WL + bi);
    }
    short8 aH[2], aL[2];
#pragma unroll
    for (int r = 0; r < 2; ++r) {
      int off = ((r << 4) + (l & 15)) * RS + kst * 32 + fragOff;
      aH[r] = *(const short8*)&AsH[off];
      aL[r] = *(const short8*)&AsL[off];
    }
#pragma unroll
    for (int r = 0; r < 2; ++r)
#pragma unroll
      for (int c = 0; c < 2; ++c) {
        acc[r][c] = __builtin_amdgcn_mfma_f32_16x16x32_bf16(aH[r], bH[c], acc[r][c], 0, 0, 0);
        acc[r][c] = __builtin_amdgcn_mfma_f32_16x16x32_bf16(aH[r], bL[c], acc[r][c], 0, 0, 0);
        acc[r][c] = __builtin_amdgcn_mfma_f32_16x16x32_bf16(aL[r], bH[c], acc[r][c], 0, 0, 0);
      }
  }

#pragma unroll
  for (int r = 0; r < 2; ++r)
#pragma unroll
    for (int c = 0; c < 2; ++c) {
      int col = ((w << 1) + c) * 16 + (l & 15);
#pragma unroll
      for (int i = 0; i < 4; ++i) {
        int row = rowBase + (r << 4) + ((l >> 4) << 2) + i;
        if (row < N) {
          float v = tanhf(acc[r][c][i]);
          out[(size_t)row * H + col] = __half_as_ushort(__float2half(v));
        }
      }
    }
}

// ---------------------------------------------------------------- pack KAN weights into padded [128][KP] (sender only)
__global__ void build_wpad(const float* __restrict__ base_w, const float* __restrict__ spline_w,
                           float* __restrict__ Wpad, int D, int KP) {
  int idx = blockIdx.x * blockDim.x + threadIdx.x;
  if (idx >= 128 * KP) return;
  int o = idx / KP, k = idx - o * KP;
  float v = 0.f;
  if (k < D) v = base_w[o * D + k];
  else if (k < 9 * D) v = spline_w[o * D * 8 + (k - D)];
  Wpad[idx] = v;
}

// ---------------------------------------------------------------- small fused KAN (sender, D=1)
template <int D>
__global__ __launch_bounds__(256) void kan_gemm(
    const float* __restrict__ x, const float* __restrict__ Wpad,
    float* __restrict__ out, int N) {
  constexpr int KP = (9 * D + 15) & ~15;
  __shared__ float As[KP][68];
  __shared__ float Bs[16][132];
  const int tid = threadIdx.x;
  const int rowBase = blockIdx.x * 64;

  for (int idx = tid; idx < 64 * D; idx += 256) {
    int nl = idx / D, i = idx - nl * D;
    int n = rowBase + nl;
    float xv = (n < N) ? x[(size_t)n * D + i] : 0.f;
    float sg = 1.f / (1.f + expf(-xv));
    float b[8];
    bspline8(xv, b);
    As[i][nl] = xv * sg;
#pragma unroll
    for (int m = 0; m < 8; ++m) As[D + i * 8 + m][nl] = b[m];
  }
  for (int idx = tid; idx < (KP - 9 * D) * 64; idx += 256) {
    int r = idx >> 6, c = idx & 63;
    As[9 * D + r][c] = 0.f;
  }

  const int rb = (tid >> 5) << 3;
  const int cb = (tid & 31) << 2;
  const int bo = tid >> 1;
  const int bk = (tid & 1) << 3;
  float acc[8][4] = {};

  for (int kc = 0; kc < KP / 16; ++kc) {
    int koff = kc << 4;
    float4 bv0 = *(const float4*)(Wpad + (size_t)bo * KP + koff + bk);
    float4 bv1 = *(const float4*)(Wpad + (size_t)bo * KP + koff + bk + 4);
    __syncthreads();
    Bs[bk + 0][bo] = bv0.x; Bs[bk + 1][bo] = bv0.y; Bs[bk + 2][bo] = bv0.z; Bs[bk + 3][bo] = bv0.w;
    Bs[bk + 4][bo] = bv1.x; Bs[bk + 5][bo] = bv1.y; Bs[bk + 6][bo] = bv1.z; Bs[bk + 7][bo] = bv1.w;
    __syncthreads();
#pragma unroll
    for (int k = 0; k < 16; ++k) {
      float4 a0 = *(const float4*)&As[koff + k][rb];
      float4 a1 = *(const float4*)&As[koff + k][rb + 4];
      float4 b = *(const float4*)&Bs[k][cb];
      float a[8] = {a0.x, a0.y, a0.z, a0.w, a1.x, a1.y, a1.z, a1.w};
      float bb[4] = {b.x, b.y, b.z, b.w};
#pragma unroll
      for (int r = 0; r < 8; ++r)
#pragma unroll
        for (int c = 0; c < 4; ++c) acc[r][c] += a[r] * bb[c];
    }
  }

#pragma unroll
  for (int r = 0; r < 8; ++r) {
    int n = rowBase + rb + r;
    if (n < N) {
      float v[4] = {tanhf(acc[r][0]), tanhf(acc[r][1]), tanhf(acc[r][2]), tanhf(acc[r][3])};
      *(float4*)(out + (size_t)n * H + cb) = *(float4*)v;
    }
  }
}

// ---------------------------------------------------------------- CSR build
// plain count (se, small)
__global__ void count_kernel(const int* __restrict__ dst, int E, int* __restrict__ cnt) {
  int i = blockIdx.x * blockDim.x + threadIdx.x;
  if (i < E) atomicAdd(&cnt[dst[i]], 1);
}

// XCD-range-partitioned count (ue): range = blockIdx&7 owns dst slice -> atomics
// stay in one XCD's L2 (blockIdx round-robins XCDs on MI355X).
__global__ __launch_bounds__(256) void count_part(const int* __restrict__ dst, int E,
                                                  int* __restrict__ cnt, int n_dst) {
  int range = blockIdx.x & 7;
  int lo = range * (n_dst >> 3);
  int hi = (range == 7) ? n_dst : lo + (n_dst >> 3);
  int stride = (gridDim.x >> 3) * 256;
  for (int i = (blockIdx.x >> 3) * 256 + threadIdx.x; i < E; i += stride) {
    int d = dst[i];
    if (d >= lo && d < hi) atomicAdd(&cnt[d], 1);
  }
}

// batched 3-phase multi-block scan (se + ue in one launch each)
__global__ __launch_bounds__(1024) void scan_p1b(
    const int* __restrict__ cnt0, const int* __restrict__ cnt1, int n,
    int* __restrict__ offs0, int* __restrict__ offs1,
    int* __restrict__ bsum0, int* __restrict__ bsum1) {
  const int* cnt = blockIdx.y ? cnt1 : cnt0;
  int* offs = blockIdx.y ? offs1 : offs0;
  int* bsum = blockIdx.y ? bsum1 : bsum0;
  __shared__ int wsum[16];
  const int tid = threadIdx.x;
  const int lane = tid & 63;
  const int wid = tid >> 6;
  int i = blockIdx.x * 1024 + tid;
  int v = (i < n) ? cnt[i] : 0;
  int x = v;
#pragma unroll
  for (int off = 1; off < 64; off <<= 1) {
    int t = __shfl_up(x, off);
    if (lane >= off) x += t;
  }
  if (lane == 63) wsum[wid] = x;
  __syncthreads();
  if (wid == 0) {
    int w = (lane < 16) ? wsum[lane] : 0;
#pragma unroll
    for (int off = 1; off < 16; off <<= 1) {
      int t = __shfl_up(w, off);
      if (lane >= off) w += t;
    }
    if (lane < 16) wsum[lane] = w;
  }
  __syncthreads();
  int excl = ((wid == 0) ? 0 : wsum[wid - 1]) + x - v;
  if (i < n) offs[i] = excl;
  if (tid == 0) bsum[blockIdx.x] = wsum[15];
}

__global__ void scan_p2b(int* __restrict__ b0, int* __restrict__ b1, int nb) {
  int wid = threadIdx.x >> 6, lane = threadIdx.x & 63;
  int* bsum = wid ? b1 : b0;
  int v = (lane < nb) ? bsum[lane] : 0;
  int x = v;
#pragma unroll
  for (int off = 1; off < 64; off <<= 1) {
    int t = __shfl_up(x, off);
    if (lane >= off) x += t;
  }
  if (lane < nb) bsum[lane] = x - v;
  if (lane == 63) bsum[nb] = x;
}

__global__ void scan_p3b(int* __restrict__ offs0, int* __restrict__ offs1,
                         int* __restrict__ cur0, int* __restrict__ cur1,
                         const int* __restrict__ bsum0, const int* __restrict__ bsum1, int n) {
  int* offs = blockIdx.y ? offs1 : offs0;
  int* cursor = blockIdx.y ? cur1 : cur0;
  const int* bsum = blockIdx.y ? bsum1 : bsum0;
  int i = blockIdx.x * blockDim.x + threadIdx.x;
  if (i < n) {
    int o = offs[i] + bsum[i >> 10];
    offs[i] = o;
    cursor[i] = o;
  }
  if (i == 0) offs[n] = bsum[(n + 1023) >> 10];
}

// plain scatter (se, small)
__global__ void scatter_kernel(const int* __restrict__ src, const int* __restrict__ dst, int E,
                               int* __restrict__ cursor, int* __restrict__ sorted_src) {
  int i = blockIdx.x * blockDim.x + threadIdx.x;
  if (i < E) {
    int p = atomicAdd(&cursor[dst[i]], 1);
    sorted_src[p] = src[i];
  }
}

// XCD-range-partitioned scatter (ue): sorted_src slice for dst-range r is
// contiguous (CSR dst-ordered), written only by blocks with blockIdx&7==r ->
// full-line L2 writebacks instead of 16x cross-XCD write amplification.
__global__ __launch_bounds__(256) void scatter_part(
    const int* __restrict__ src, const int* __restrict__ dst, int E,
    int* __restrict__ cursor, int* __restrict__ sorted_src, int n_dst) {
  int range = blockIdx.x & 7;
  int lo = range * (n_dst >> 3);
  int hi = (range == 7) ? n_dst : lo + (n_dst >> 3);
  int stride = (gridDim.x >> 3) * 256;
  for (int i = (blockIdx.x >> 3) * 256 + threadIdx.x; i < E; i += stride) {
    int d = dst[i];
    if (d >= lo && d < hi) {
      int p = atomicAdd(&cursor[d], 1);
      sorted_src[p] = src[i];
    }
  }
}

// mean aggregation (fp32): one wave per dst, float2 lanes, 4-deep MLP
__global__ __launch_bounds__(256) void aggregate_mean(
    const float* __restrict__ feat, const int* __restrict__ offs,
    const int* __restrict__ sorted_src, float* __restrict__ agg, int n_dst) {
  int d = (blockIdx.x << 2) + (threadIdx.x >> 6);
  if (d >= n_dst) return;
  int lane = threadIdx.x & 63;
  int s0 = offs[d], s1 = offs[d + 1];
  float ax = 0.f, ay = 0.f;
  const float* base = feat + (lane << 1);
  int k = s0;
  for (; k + 3 < s1; k += 4) {
    int i0 = sorted_src[k], i1 = sorted_src[k + 1];
    int i2 = sorted_src[k + 2], i3 = sorted_src[k + 3];
    float2 v0 = *(const float2*)(base + (size_t)i0 * H);
    float2 v1 = *(const float2*)(base + (size_t)i1 * H);
    float2 v2 = *(const float2*)(base + (size_t)i2 * H);
    float2 v3 = *(const float2*)(base + (size_t)i3 * H);
    ax += (v0.x + v1.x) + (v2.x + v3.x);
    ay += (v0.y + v1.y) + (v2.y + v3.y);
  }
  for (; k < s1; ++k) {
    int i0 = sorted_src[k];
    float2 v0 = *(const float2*)(base + (size_t)i0 * H);
    ax += v0.x;
    ay += v0.y;
  }
  float inv = 1.f / fmaxf((float)(s1 - s0), 1.f);
  *(float2*)(agg + (size_t)d * H + (lane << 1)) = make_float2(ax * inv, ay * inv);
}

// mean aggregation (fp16 source), 4-deep MLP
__global__ __launch_bounds__(256) void aggregate_mean_f16(
    const unsigned short* __restrict__ feat, const int* __restrict__ offs,
    const int* __restrict__ sorted_src, float* __restrict__ agg, int n_dst) {
  int d = (blockIdx.x << 2) + (threadIdx.x >> 6);
  if (d >= n_dst) return;
  int lane = threadIdx.x & 63;
  int s0 = offs[d], s1 = offs[d + 1];
  float ax = 0.f, ay = 0.f;
  const unsigned short* base = feat + (lane << 1);
  int k = s0;
  for (; k + 3 < s1; k += 4) {
    int i0 = sorted_src[k], i1 = sorted_src[k + 1];
    int i2 = sorted_src[k + 2], i3 = sorted_src[k + 3];
    float2 f0 = __half22float2(*(const __half2*)(base + (size_t)i0 * H));
    float2 f1 = __half22float2(*(const __half2*)(base + (size_t)i1 * H));
    float2 f2 = __half22float2(*(const __half2*)(base + (size_t)i2 * H));
    float2 f3 = __half22float2(*(const __half2*)(base + (size_t)i3 * H));
    ax += (f0.x + f1.x) + (f2.x + f3.x);
    ay += (f0.y + f1.y) + (f2.y + f3.y);
  }
  for (; k < s1; ++k) {
    int i0 = sorted_src[k];
    float2 f0 = __half22float2(*(const __half2*)(base + (size_t)i0 * H));
    ax += f0.x;
    ay += f0.y;
  }
  float inv = 1.f / fmaxf((float)(s1 - s0), 1.f);
  *(float2*)(agg + (size_t)d * H + (lane << 1)) = make_float2(ax * inv, ay * inv);
}

// ---------------------------------------------------------------- BatchNorm stats (combined = [eh | e])
__global__ void bn_stats(const float* __restrict__ eh, const float* __restrict__ e, int M,
                         double* __restrict__ sums) {
  int t = threadIdx.x;
  double s = 0.0, s2 = 0.0;
  for (int r = blockIdx.x; r < M; r += gridDim.x) {
    float v = (t < 128) ? eh[(size_t)r * 128 + t] : e[(size_t)r * 128 + (t - 128)];
    s += v;
    s2 += (double)v * v;
  }
  atomicAdd(&sums[t], s);
  atomicAdd(&sums[256 + t], s2);
}

__global__ void bn_finalize(const double* __restrict__ sums, int M,
                            const float* __restrict__ gamma, const float* __restrict__ beta,
                            float* __restrict__ scale, float* __restrict__ shift) {
  int c = threadIdx.x;
  if (c < 256) {
    double mu = sums[c] / M;
    double var = sums[256 + c] / M - mu * mu;
    float rstd = 1.0f / sqrtf((float)var + 1e-5f);
    float g = gamma[c] * rstd;
    scale[c] = g;
    shift[c] = beta[c] - (float)mu * g;
  }
}

// ---------------------------------------------------------------- classifier KAN (persistent, HW-verified round 9)
__global__ __launch_bounds__(256) void classifier_kan(
    const float* __restrict__ eh, const float* __restrict__ e,
    const float* __restrict__ scale, const float* __restrict__ shift,
    const float* __restrict__ base_w, const float* __restrict__ spline_w,
    float* __restrict__ out, int M) {
  __shared__ float w0p[16][256];
  __shared__ float w1p[16][256];
  __shared__ float wb0[256], wb1[256];
  __shared__ float sc[256], sh[256];
  int tid = threadIdx.x;
  for (int idx = tid; idx < 16 * 256; idx += 256) {
    int t = idx >> 8, c = idx & 255;
    int m = t - 4;
    float v0 = 0.f, v1 = 0.f;
    if (m >= 0 && m < 8) {
      v0 = spline_w[((size_t)c) * 8 + m];
      v1 = spline_w[((size_t)(256 + c)) * 8 + m];
    }
    w0p[t][c] = v0;
    w1p[t][c] = v1;
  }
  wb0[tid] = base_w[tid];
  wb1[tid] = base_w[256 + tid];
  sc[tid] = scale[tid];
  sh[tid] = shift[tid];
  __syncthreads();
  int wave = tid >> 6, lane = tid & 63;
  for (int r = blockIdx.x * 4 + wave; r < M; r += gridDim.x * 4) {
    float a0 = 0.f, a1 = 0.f;
#pragma unroll
    for (int mm = 0; mm < 4; ++mm) {
      int c = lane + (mm << 6);
      float xv = (c < 128) ? eh[(size_t)r * 128 + c] : e[(size_t)r * 128 + (c - 128)];
      float y = xv * sc[c] + sh[c];
      float sg = 1.f / (1.f + expf(-y));
      float si = y * sg;
      a0 += si * wb0[c];
      a1 += si * wb1[c];
      int i0;
      float P0, P1, P2, P3;
      spline_pieces(y, i0, P0, P1, P2, P3);
      i0 = i0 < -1 ? -1 : (i0 > 11 ? 11 : i0);
      int t0 = i0 + 4;
      a0 += P0 * w0p[t0][c] + P1 * w0p[t0 - 1][c] + P2 * w0p[t0 - 2][c] + P3 * w0p[t0 - 3][c];
      a1 += P0 * w1p[t0][c] + P1 * w1p[t0 - 1][c] + P2 * w1p[t0 - 2][c] + P3 * w1p[t0 - 3][c];
    }
#pragma unroll
    for (int off = 32; off >= 1; off >>= 1) {
      a0 += __shfl_down(a0, off);
      a1 += __shfl_down(a1, off);
    }
    if (lane == 0) {
      out[(size_t)r * 2] = a0;
      out[(size_t)r * 2 + 1] = a1;
    }
  }
}

// ---------------------------------------------------------------- launch
extern "C" void kernel_launch(void* const* d_in, const int* in_sizes, int n_in,
                              void* d_out, int out_size, void* d_ws, size_t ws_size,
                              hipStream_t stream) {
  const float* email_x   = (const float*)d_in[0];
  const float* url_x     = (const float*)d_in[1];
  const float* sender_x  = (const float*)d_in[2];
  const float* W_email   = (const float*)d_in[3];
  const float* b_email   = (const float*)d_in[4];
  const float* url_bw    = (const float*)d_in[5];
  const float* url_sw    = (const float*)d_in[6];
  const float* snd_bw    = (const float*)d_in[7];
  const float* snd_sw    = (const float*)d_in[8];
  const float* Wl_se     = (const float*)d_in[9];
  const float* bl_se     = (const float*)d_in[10];
  const float* Wr_se     = (const float*)d_in[11];
  // d_in[12..14]: eu SAGE weights — dead code in the reference (result unused)
  const float* Wl_ue     = (const float*)d_in[15];
  const float* bl_ue     = (const float*)d_in[16];
  const float* Wr_ue     = (const float*)d_in[17];
  const float* bn_gamma  = (const float*)d_in[18];
  const float* bn_beta   = (const float*)d_in[19];
  const float* cls_bw    = (const float*)d_in[20];
  const float* cls_sw    = (const float*)d_in[21];
  const int*   se_src    = (const int*)d_in[22];
  const int*   se_dst    = (const int*)d_in[23];
  // d_in[24..25]: eu edges — dead
  const int*   ue_src    = (const int*)d_in[26];
  const int*   ue_dst    = (const int*)d_in[27];

  const int N_E = in_sizes[0] / 768;
  const int N_U = in_sizes[1] / 8;
  const int N_S = in_sizes[2];
  const int E_SE = in_sizes[22];
  const int E_UE = in_sizes[26];

  char* ws = (char*)d_ws;
  size_t off = 0;
  auto alloc = [&](size_t bytes) -> void* {
    void* p = ws + off;
    off = (off + bytes + 255) & ~(size_t)255;
    return p;
  };

  float* e      = (float*)alloc((size_t)N_E * H * 4);
  // u is fp16; buffer reused later for fp32 eh (N_E*H*4 = 15.4MB < N_U*H*2 = 51.2MB)
  unsigned short* u = (unsigned short*)alloc((size_t)N_U * H * 2);
  float* s      = (float*)alloc((size_t)N_S * H * 4);
  float* agg_s  = (float*)alloc((size_t)N_E * H * 4);
  float* agg_u  = (float*)alloc((size_t)N_E * H * 4);
  float* wpad_s = (float*)alloc((size_t)128 * 16 * 4);
  unsigned short* wEH = (unsigned short*)alloc((size_t)24 * 8 * 64 * 8 * 2);
  unsigned short* wEL = (unsigned short*)alloc((size_t)24 * 8 * 64 * 8 * 2);
  unsigned short* wHH = (unsigned short*)alloc((size_t)12 * 8 * 64 * 8 * 2);
  unsigned short* wHL = (unsigned short*)alloc((size_t)12 * 8 * 64 * 8 * 2);
  unsigned short* wKH = (unsigned short*)alloc((size_t)3 * 8 * 64 * 8 * 2);
  unsigned short* wKL = (unsigned short*)alloc((size_t)3 * 8 * 64 * 8 * 2);
  // cnt arrays adjacent -> single fused memset
  int* cnt_se   = (int*)alloc((size_t)N_E * 4);
  int* cnt_ue   = (int*)alloc((size_t)N_E * 4);
  int* offs_se  = (int*)alloc(((size_t)N_E + 1) * 4);
  int* cur_se   = (int*)alloc((size_t)N_E * 4);
  int* srt_se   = (int*)alloc((size_t)E_SE * 4);
  int* offs_ue  = (int*)alloc(((size_t)N_E + 1) * 4);
  int* cur_ue   = (int*)alloc((size_t)N_E * 4);
  int* srt_ue   = (int*)alloc((size_t)E_UE * 4);
  int* bsum_se  = (int*)alloc(64 * 4);
  int* bsum_ue  = (int*)alloc(64 * 4);
  double* bnsum = (double*)alloc(512 * 8);
  float* scale  = (float*)alloc(256 * 4);
  float* shift  = (float*)alloc(256 * 4);
  // u (fp16) is dead after aggregate_mean_f16; reuse its space for fp32 email_h
  float* eh = (float*)u;

  // fused memset over both cnt arrays (adjacent allocations)
  hipMemsetAsync(cnt_se, 0, (size_t)((char*)cnt_ue - (char*)cnt_se) + (size_t)N_E * 4, stream);
  hipMemsetAsync(bnsum, 0, 512 * 8, stream);

  // pack weights (4 launches, was 7)
  pack_wfrag<<<(24 * 512 + 255) / 256, 256, 0, stream>>>(W_email, nullptr, 768, 24, wEH, wEL, 0);
  pack_wfrag_h<<<(12 * 512 + 255) / 256, 256, 0, stream>>>(Wl_se, Wl_ue, Wr_se, Wr_ue, wHH, wHL);
  pack_kan_frag<<<(3 * 512 + 255) / 256, 256, 0, stream>>>(url_bw, url_sw, wKH, wKL);
  build_wpad<<<(128 * 16 + 255) / 256, 256, 0, stream>>>(snd_bw, snd_sw, wpad_s, 1, 16);

  // node encoders
  mfma_gemm<1, 24, 1><<<(N_E + 31) / 32, 256, 0, stream>>>(
      N_E, email_x, nullptr, nullptr, wEH, wEL, b_email, nullptr, e);
  kan_mfma8<<<(N_U + 31) / 32, 256, 0, stream>>>(url_x, wKH, wKL, u, N_U);
  kan_gemm<1><<<(N_S + 63) / 64, 256, 0, stream>>>(sender_x, wpad_s, s, N_S);

  // CSR build (ue: XCD-range-partitioned count+scatter; batched scans)
  const int nb = (N_E + 1023) / 1024;
  count_kernel<<<(E_SE + 255) / 256, 256, 0, stream>>>(se_dst, E_SE, cnt_se);
  count_part<<<2048, 256, 0, stream>>>(ue_dst, E_UE, cnt_ue, N_E);
  scan_p1b<<<dim3(nb, 2), 1024, 0, stream>>>(cnt_se, cnt_ue, N_E, offs_se, offs_ue,
                                             bsum_se, bsum_ue);
  scan_p2b<<<1, 128, 0, stream>>>(bsum_se, bsum_ue, nb);
  scan_p3b<<<dim3((N_E + 255) / 256, 2), 256, 0, stream>>>(offs_se, offs_ue, cur_se, cur_ue,
                                                           bsum_se, bsum_ue, N_E);
  scatter_kernel<<<(E_SE + 255) / 256, 256, 0, stream>>>(se_src, se_dst, E_SE, cur_se, srt_se);
  scatter_part<<<2048, 256, 0, stream>>>(ue_src, ue_dst, E_UE, cur_ue, srt_ue, N_E);

  // mean aggregation (gather, no float atomics)
  aggregate_mean<<<(N_E + 3) / 4, 256, 0, stream>>>(s, offs_se, srt_se, agg_s, N_E);
  aggregate_mean_f16<<<(N_E + 3) / 4, 256, 0, stream>>>(u, offs_ue, srt_ue, agg_u, N_E);

  // fused email_h = lrelu(0.5*(agg_s@Wl_se^T + agg_u@Wl_ue^T + e@(Wr_se+Wr_ue)^T + bl_se + bl_ue))
  mfma_gemm<3, 4, 2><<<(N_E + 31) / 32, 256, 0, stream>>>(
      N_E, agg_s, agg_u, e, wHH, wHL, bl_se, bl_ue, eh);

  // batchnorm over combined=[eh|e], then classifier KAN (BN fused, persistent blocks)
  bn_stats<<<256, 256, 0, stream>>>(eh, e, N_E, bnsum);
  bn_finalize<<<1, 256, 0, stream>>>(bnsum, N_E, bn_gamma, bn_beta, scale, shift);
  classifier_kan<<<512, 256, 0, stream>>>(
      eh, e, scale, shift, cls_bw, cls_sw, (float*)d_out, N_E);
}